// Round 5
// baseline (459.328 us; speedup 1.0000x reference)
//
#include <hip/hip_runtime.h>
#include <hip/hip_fp16.h>

#define N_NODES 50000
#define N_EDGES 1600000
#define FIN 256
#define HD 128          // HEADS*HIDDEN
#define NHEADS 4
#define C2 16           // NUM_CLASSES
#define NEG 0.2f
#define NCH 98          // ceil(50000/512)

__device__ __forceinline__ float elu1(float x) { return x > 0.f ? x : __expf(x) - 1.f; }
__device__ __forceinline__ float lexp(float e) { return __expf(e > 0.f ? e : NEG * e); }

// ---------------- CSR build ----------------

__global__ void k_hist(const int* __restrict__ dst, int* __restrict__ deg) {
    int i = blockIdx.x * blockDim.x + threadIdx.x;
    int stride = gridDim.x * blockDim.x;
    for (; i < N_EDGES; i += stride) atomicAdd(&deg[dst[i]], 1);
}

__global__ void k_chunksum(const int* __restrict__ deg, int* __restrict__ chunksum) {
    __shared__ int s[256];
    int b = blockIdx.x, t = threadIdx.x;
    int i0 = b * 512 + t, i1 = i0 + 256;
    int v = 0;
    if (i0 < N_NODES) v += deg[i0];
    if (i1 < N_NODES) v += deg[i1];
    s[t] = v; __syncthreads();
    for (int off = 128; off > 0; off >>= 1) {
        if (t < off) s[t] += s[t + off];
        __syncthreads();
    }
    if (t == 0) chunksum[b] = s[0];
}

__global__ void k_scanchunks(const int* __restrict__ chunksum, int* __restrict__ chunkoff) {
    __shared__ int s[128];
    int t = threadIdx.x;  // blockDim = 128
    int v = (t < NCH) ? chunksum[t] : 0;
    s[t] = v; __syncthreads();
    for (int off = 1; off < 128; off <<= 1) {
        int u = (t >= off) ? s[t - off] : 0;
        __syncthreads();
        s[t] += u;
        __syncthreads();
    }
    chunkoff[t] = s[t] - v;  // exclusive
}

__global__ void k_scanfinal(const int* __restrict__ deg, const int* __restrict__ chunkoff,
                            int* __restrict__ rowstart, int* __restrict__ cursor) {
    __shared__ int s[256];
    int b = blockIdx.x, t = threadIdx.x;
    int i0 = b * 512 + 2 * t, i1 = i0 + 1;
    int a0 = (i0 < N_NODES) ? deg[i0] : 0;
    int a1 = (i1 < N_NODES) ? deg[i1] : 0;
    int pair = a0 + a1;
    s[t] = pair; __syncthreads();
    for (int off = 1; off < 256; off <<= 1) {
        int u = (t >= off) ? s[t - off] : 0;
        __syncthreads();
        s[t] += u;
        __syncthreads();
    }
    int excl = s[t] - pair + chunkoff[b];
    if (i0 <= N_NODES) { rowstart[i0] = excl; if (i0 < N_NODES) cursor[i0] = excl; }
    int e1 = excl + a0;
    if (i1 <= N_NODES) { rowstart[i1] = e1; if (i1 < N_NODES) cursor[i1] = e1; }
}

// Scatter: 4 edges per thread, int4 loads, 4 independent atomics in flight.
__global__ __launch_bounds__(256) void k_scatter(
        const int* __restrict__ src, const int* __restrict__ dst,
        int* __restrict__ cursor, int* __restrict__ sorted_src) {
    int t = blockIdx.x * blockDim.x + threadIdx.x;
    if (t >= N_EDGES / 4) return;   // 400000 threads exactly cover 1.6M edges
    int4 s4 = ((const int4*)src)[t];
    int4 d4 = ((const int4*)dst)[t];
    int p0 = atomicAdd(&cursor[d4.x], 1);
    int p1 = atomicAdd(&cursor[d4.y], 1);
    int p2 = atomicAdd(&cursor[d4.z], 1);
    int p3 = atomicAdd(&cursor[d4.w], 1);
    sorted_src[p0] = s4.x;
    sorted_src[p1] = s4.y;
    sorted_src[p2] = s4.z;
    sorted_src[p3] = s4.w;
}

// ---------------- Layer 1 GEMM: feat1 = x @ W1 (fp16 out), fused el1/er1 ----------------

__global__ __launch_bounds__(256) void k_gemm1(
        const float* __restrict__ x, const float* __restrict__ W1,
        const float* __restrict__ al1, const float* __restrict__ ar1,
        __half* __restrict__ feat1h, float* __restrict__ el1, float* __restrict__ er1) {
    __shared__ float xs[16 * 128];   // [kk][node] transposed x tile, 8 KB
    __shared__ float ws[16 * 128];   // [kk][col]  native W1 tile,   8 KB
    int tid = threadIdx.x;
    int nb = blockIdx.x * 128;
    int ct = tid & 15;               // col-thread: cols ct*8 .. ct*8+7
    int nt = tid >> 4;               // node-thread: nodes nt*8 .. nt*8+7

    float acc[8][8];
    #pragma unroll
    for (int n = 0; n < 8; n++)
        #pragma unroll
        for (int c = 0; c < 8; c++) acc[n][c] = 0.f;

    int lnode = tid & 127;
    int kg = tid >> 7;               // 0/1: which 8 of the 16 k's this thread stages
    int gnode = nb + lnode; if (gnode >= N_NODES) gnode = N_NODES - 1;
    const float4* xrow = (const float4*)(x + (size_t)gnode * FIN);
    const float4* W14 = (const float4*)W1;

    for (int k0 = 0; k0 < FIN; k0 += 16) {
        float4 a0 = xrow[(k0 >> 2) + kg * 2];
        float4 a1 = xrow[(k0 >> 2) + kg * 2 + 1];
        float4 w0 = W14[(size_t)k0 * 32 + tid];
        float4 w1 = W14[(size_t)k0 * 32 + tid + 256];
        __syncthreads();
        int kb = kg * 8;
        xs[(kb + 0) * 128 + lnode] = a0.x;
        xs[(kb + 1) * 128 + lnode] = a0.y;
        xs[(kb + 2) * 128 + lnode] = a0.z;
        xs[(kb + 3) * 128 + lnode] = a0.w;
        xs[(kb + 4) * 128 + lnode] = a1.x;
        xs[(kb + 5) * 128 + lnode] = a1.y;
        xs[(kb + 6) * 128 + lnode] = a1.z;
        xs[(kb + 7) * 128 + lnode] = a1.w;
        ((float4*)ws)[tid] = w0;
        ((float4*)ws)[tid + 256] = w1;
        __syncthreads();
        #pragma unroll
        for (int kk = 0; kk < 16; kk++) {
            float4 xa = ((const float4*)xs)[kk * 32 + nt * 2];
            float4 xb = ((const float4*)xs)[kk * 32 + nt * 2 + 1];
            float4 wa = ((const float4*)ws)[kk * 32 + ct * 2];
            float4 wb = ((const float4*)ws)[kk * 32 + ct * 2 + 1];
            float xn[8] = {xa.x, xa.y, xa.z, xa.w, xb.x, xb.y, xb.z, xb.w};
            float wc[8] = {wa.x, wa.y, wa.z, wa.w, wb.x, wb.y, wb.z, wb.w};
            #pragma unroll
            for (int n = 0; n < 8; n++)
                #pragma unroll
                for (int c = 0; c < 8; c++)
                    acc[n][c] += xn[n] * wc[c];
        }
    }

    float alv[8], arv[8];
    #pragma unroll
    for (int c = 0; c < 8; c++) { alv[c] = al1[ct * 8 + c]; arv[c] = ar1[ct * 8 + c]; }
    int head = ct >> 2;
    #pragma unroll
    for (int n = 0; n < 8; n++) {
        int node = nb + nt * 8 + n;
        bool ok = node < N_NODES;
        if (ok) {
            __half2 ph[4];
            #pragma unroll
            for (int c2 = 0; c2 < 4; c2++)
                ph[c2] = __floats2half2_rn(acc[n][2 * c2], acc[n][2 * c2 + 1]);
            *(float4*)(feat1h + (size_t)node * HD + ct * 8) = *(float4*)ph;
        }
        float pl = 0.f, pr = 0.f;
        #pragma unroll
        for (int c = 0; c < 8; c++) { pl += acc[n][c] * alv[c]; pr += acc[n][c] * arv[c]; }
        pl += __shfl_xor(pl, 1); pl += __shfl_xor(pl, 2);
        pr += __shfl_xor(pr, 1); pr += __shfl_xor(pr, 2);
        if (ok && (ct & 3) == 0) {
            el1[node * 4 + head] = pl;
            er1[node * 4 + head] = pr;
        }
    }
}

// ---------------- Layer 1 aggregation: wave per dst, 4 edges x 16 col-lanes ----------------
// weight recomputed from el1 gather (L2-resident 800 KB) + wave-level er1.

__global__ __launch_bounds__(256) void k_agg1(
        const int* __restrict__ rowstart, const int* __restrict__ sorted_src,
        const float* __restrict__ el1, const float* __restrict__ er1,
        const __half* __restrict__ feat1h, const float* __restrict__ b1,
        float* __restrict__ h) {
    int tid = threadIdx.x;
    int d = blockIdx.x * 4 + (tid >> 6);   // 50000 % 4 == 0
    int lane = tid & 63;
    int eg = lane >> 4;                    // edge group 0..3
    int cl = lane & 15;                    // col-lane: cols 8*cl..8*cl+7
    int head = cl >> 2;
    float er = er1[d * 4 + head];
    int start = rowstart[d], end = rowstart[d + 1];
    float acc[8];
    #pragma unroll
    for (int k = 0; k < 8; k++) acc[k] = 0.f;
    float wsum = 0.f;

    for (int i = start; i < end; i += 8) {
        int e0 = i + eg, e1 = i + 4 + eg;
        bool ok0 = e0 < end, ok1 = e1 < end;
        int e0c = ok0 ? e0 : end - 1;
        int e1c = ok1 ? e1 : end - 1;
        int s0 = sorted_src[e0c];
        int s1 = sorted_src[e1c];
        float el0v = el1[s0 * 4 + head];
        float el1v = el1[s1 * 4 + head];
        float4 r0 = *(const float4*)(feat1h + (size_t)s0 * HD + cl * 8);
        float4 r1 = *(const float4*)(feat1h + (size_t)s1 * HD + cl * 8);
        float w0 = ok0 ? lexp(el0v + er) : 0.f;
        float w1 = ok1 ? lexp(el1v + er) : 0.f;
        const __half2* p0 = (const __half2*)&r0;
        const __half2* p1 = (const __half2*)&r1;
        #pragma unroll
        for (int q = 0; q < 4; q++) {
            float2 f0 = __half22float2(p0[q]);
            float2 f1 = __half22float2(p1[q]);
            acc[2 * q]     += w0 * f0.x + w1 * f1.x;
            acc[2 * q + 1] += w0 * f0.y + w1 * f1.y;
        }
        wsum += w0 + w1;
    }
    #pragma unroll
    for (int k = 0; k < 8; k++) {
        acc[k] += __shfl_xor(acc[k], 16);
        acc[k] += __shfl_xor(acc[k], 32);
    }
    wsum += __shfl_xor(wsum, 16);
    wsum += __shfl_xor(wsum, 32);
    if (eg == 0) {
        float inv = 1.f / fmaxf(wsum, 1e-9f);
        float v[8];
        #pragma unroll
        for (int k = 0; k < 8; k++) v[k] = elu1(acc[k] * inv + b1[cl * 8 + k]);
        float4* hp = (float4*)(h + (size_t)d * HD + cl * 8);
        hp[0] = make_float4(v[0], v[1], v[2], v[3]);
        hp[1] = make_float4(v[4], v[5], v[6], v[7]);
    }
}

// ---------------- Layer 2 GEMM: feat2 = h @ W2, fused el2/er2 ----------------

__global__ __launch_bounds__(256) void k_gemm2(
        const float* __restrict__ h, const float* __restrict__ W2,
        const float* __restrict__ al2, const float* __restrict__ ar2,
        float* __restrict__ feat2, float* __restrict__ el2, float* __restrict__ er2) {
    __shared__ float hs[16 * 132];
    __shared__ float w2t[16 * 132];
    int tid = threadIdx.x;
    int nb = blockIdx.x * 16;  // 50000 % 16 == 0
    for (int idx = tid; idx < 512; idx += 256) {
        int row = idx >> 5, kk = idx & 31;
        ((float4*)(hs + row * 132))[kk] = ((const float4*)h)[(size_t)(nb + row) * 32 + kk];
    }
    for (int idx = tid; idx < 2048; idx += 256) {
        int k = idx >> 4, c = idx & 15;
        w2t[c * 132 + k] = W2[idx];
    }
    __syncthreads();
    int nl = tid >> 4, col = tid & 15;
    const float4* hv = (const float4*)(hs + nl * 132);
    const float4* wv = (const float4*)(w2t + col * 132);
    float acc = 0.f;
    #pragma unroll
    for (int kk = 0; kk < 32; kk++) {
        float4 a = hv[kk], w = wv[kk];
        acc += a.x * w.x + a.y * w.y + a.z * w.z + a.w * w.w;
    }
    int node = nb + nl;
    feat2[node * 16 + col] = acc;
    float pl = acc * al2[col], pr = acc * ar2[col];
    #pragma unroll
    for (int m = 8; m >= 1; m >>= 1) {
        pl += __shfl_xor(pl, m);
        pr += __shfl_xor(pr, m);
    }
    if (col == 0) { el2[node] = pl; er2[node] = pr; }
}

// ---------------- Layer 2 aggregation: wave per dst, 16 edges x 4 col-lanes ----------------

__global__ __launch_bounds__(256) void k_agg2(
        const int* __restrict__ rowstart, const int* __restrict__ sorted_src,
        const float* __restrict__ el2, const float* __restrict__ er2,
        const float* __restrict__ feat2, const float* __restrict__ b2,
        float* __restrict__ out) {
    int tid = threadIdx.x;
    int d = blockIdx.x * 4 + (tid >> 6);   // 50000 % 4 == 0
    int lane = tid & 63;
    int eg = lane >> 2;                    // edge group 0..15
    int cq = lane & 3;                     // cols 4*cq..4*cq+3
    float er = er2[d];
    int start = rowstart[d], end = rowstart[d + 1];
    float4 acc = make_float4(0.f, 0.f, 0.f, 0.f);
    float wsum = 0.f;
    for (int i = start; i < end; i += 16) {
        int e = i + eg;
        bool ok = e < end;
        int ec = ok ? e : end - 1;
        int s = sorted_src[ec];
        float elv = el2[s];
        float4 f = ((const float4*)feat2)[(size_t)s * 4 + cq];
        float ev = elv + er;
        float wr = __expf(ev > 0.f ? ev : NEG * ev);
        float w = ok ? wr : 0.f;
        acc.x += w * f.x; acc.y += w * f.y; acc.z += w * f.z; acc.w += w * f.w;
        wsum += w;
    }
    #pragma unroll
    for (int m = 4; m <= 32; m <<= 1) {
        acc.x += __shfl_xor(acc.x, m);
        acc.y += __shfl_xor(acc.y, m);
        acc.z += __shfl_xor(acc.z, m);
        acc.w += __shfl_xor(acc.w, m);
        wsum  += __shfl_xor(wsum, m);
    }
    if (lane < 4) {
        float inv = 1.f / fmaxf(wsum, 1e-9f);
        float4 bv = ((const float4*)b2)[cq];
        float4 o = make_float4(acc.x * inv + bv.x, acc.y * inv + bv.y,
                               acc.z * inv + bv.z, acc.w * inv + bv.w);
        ((float4*)out)[(size_t)d * 4 + cq] = o;
    }
}

// ---------------- launch ----------------

extern "C" void kernel_launch(void* const* d_in, const int* in_sizes, int n_in,
                              void* d_out, int out_size, void* d_ws, size_t ws_size,
                              hipStream_t stream) {
    const float* x   = (const float*)d_in[0];
    const int*   src = (const int*)d_in[1];
    const int*   dst = (const int*)d_in[2];
    const float* W1  = (const float*)d_in[3];
    const float* b1  = (const float*)d_in[4];
    const float* al1 = (const float*)d_in[5];
    const float* ar1 = (const float*)d_in[6];
    const float* W2  = (const float*)d_in[7];
    const float* b2  = (const float*)d_in[8];
    const float* al2 = (const float*)d_in[9];
    const float* ar2 = (const float*)d_in[10];
    float* out = (float*)d_out;

    char* ws = (char*)d_ws;
    size_t off = 0;
    auto alloc = [&](size_t bytes) -> char* {
        char* p = ws + off;
        off += (bytes + 255) & ~(size_t)255;
        return p;
    };
    __half* feat1h    = (__half*)alloc((size_t)N_NODES * HD * 2);
    float* h          = (float*)alloc((size_t)N_NODES * HD * 4);
    float* el1        = (float*)alloc((size_t)N_NODES * 4 * 4);
    float* er1        = (float*)alloc((size_t)N_NODES * 4 * 4);
    float* feat2      = (float*)alloc((size_t)N_NODES * C2 * 4);
    float* el2        = (float*)alloc((size_t)N_NODES * 4);
    float* er2        = (float*)alloc((size_t)N_NODES * 4);
    int*   deg        = (int*)alloc((size_t)N_NODES * 4);
    int*   rowstart   = (int*)alloc((size_t)(N_NODES + 1) * 4);
    int*   cursor     = (int*)alloc((size_t)N_NODES * 4);
    int*   chunksum   = (int*)alloc(128 * 4);
    int*   chunkoff   = (int*)alloc(128 * 4);
    int*   sorted_src = (int*)alloc((size_t)N_EDGES * 4);

    hipMemsetAsync(deg, 0, (size_t)N_NODES * 4, stream);
    k_hist<<<2048, 256, 0, stream>>>(dst, deg);
    k_chunksum<<<NCH, 256, 0, stream>>>(deg, chunksum);
    k_scanchunks<<<1, 128, 0, stream>>>(chunksum, chunkoff);
    k_scanfinal<<<NCH, 256, 0, stream>>>(deg, chunkoff, rowstart, cursor);
    k_scatter<<<(N_EDGES / 4 + 255) / 256, 256, 0, stream>>>(src, dst, cursor, sorted_src);
    k_gemm1<<<(N_NODES + 127) / 128, 256, 0, stream>>>(x, W1, al1, ar1, feat1h, el1, er1);
    k_agg1<<<N_NODES / 4, 256, 0, stream>>>(rowstart, sorted_src, el1, er1, feat1h, b1, h);
    k_gemm2<<<N_NODES / 16, 256, 0, stream>>>(h, W2, al2, ar2, feat2, el2, er2);
    k_agg2<<<N_NODES / 4, 256, 0, stream>>>(rowstart, sorted_src, el2, er2, feat2, b2, out);
}

// Round 6
// 330.174 us; speedup vs baseline: 1.3912x; 1.3912x over previous
//
#include <hip/hip_runtime.h>
#include <hip/hip_fp16.h>

#define N_NODES 50000
#define N_EDGES 1600000
#define FIN 256
#define HD 128          // HEADS*HIDDEN
#define NHEADS 4
#define C2 16           // NUM_CLASSES
#define NEG 0.2f

// bucketed counting-sort CSR build
#define EBLK 4096
#define NBLK 391        // ceil(N_EDGES/EBLK)
#define NBUCK 391       // ceil(N_NODES/128)
#define BSH 7
#define BMASK 127
#define MAXB 5120       // bucket capacity: mean 4096, sigma ~64 -> +16 sigma

__device__ __forceinline__ float elu1(float x) { return x > 0.f ? x : __expf(x) - 1.f; }
__device__ __forceinline__ float lexp(float e) { return __expf(e > 0.f ? e : NEG * e); }

// ---------------- CSR build: bucketed counting sort ----------------

__global__ __launch_bounds__(256) void k_bhist(const int* __restrict__ dst,
                                               int* __restrict__ ghist) {
    __shared__ int lh[NBUCK];
    int tid = threadIdx.x, b = blockIdx.x;
    for (int t = tid; t < NBUCK; t += 256) lh[t] = 0;
    __syncthreads();
    int base = b * EBLK;
    int nq = (min(EBLK, N_EDGES - base)) >> 2;
    const int4* d4 = (const int4*)(dst + base);
    for (int q = tid; q < nq; q += 256) {
        int4 d = d4[q];
        atomicAdd(&lh[d.x >> BSH], 1);
        atomicAdd(&lh[d.y >> BSH], 1);
        atomicAdd(&lh[d.z >> BSH], 1);
        atomicAdd(&lh[d.w >> BSH], 1);
    }
    __syncthreads();
    for (int t = tid; t < NBUCK; t += 256) ghist[t * NBLK + b] = lh[t];
}

__global__ __launch_bounds__(512) void k_bscan(int* __restrict__ ghist,
                                               int* __restrict__ bucket_base,
                                               int* __restrict__ rowstart) {
    __shared__ int s[512];
    int t = threadIdx.x;
    int run = 0;
    if (t < NBUCK) {
        for (int b = 0; b < NBLK; b++) {
            int v = ghist[t * NBLK + b];
            ghist[t * NBLK + b] = run;   // within-bucket exclusive prefix per block
            run += v;
        }
    }
    s[t] = (t < NBUCK) ? run : 0;
    __syncthreads();
    for (int off = 1; off < 512; off <<= 1) {
        int u = (t >= off) ? s[t - off] : 0;
        __syncthreads();
        s[t] += u;
        __syncthreads();
    }
    if (t < NBUCK) bucket_base[t] = s[t] - run;  // exclusive over buckets
    if (t == 0) { bucket_base[NBUCK] = N_EDGES; rowstart[N_NODES] = N_EDGES; }
}

__global__ __launch_bounds__(256) void k_bscatter(
        const int* __restrict__ src, const int* __restrict__ dst,
        const int* __restrict__ ghist, const int* __restrict__ bucket_base,
        int* __restrict__ ebuf) {
    __shared__ int lcur[NBUCK];
    int tid = threadIdx.x, b = blockIdx.x;
    for (int t = tid; t < NBUCK; t += 256)
        lcur[t] = bucket_base[t] + ghist[t * NBLK + b];
    __syncthreads();
    int base = b * EBLK;
    int nq = (min(EBLK, N_EDGES - base)) >> 2;
    const int4* s4 = (const int4*)(src + base);
    const int4* d4 = (const int4*)(dst + base);
    for (int q = tid; q < nq; q += 256) {
        int4 s = s4[q];
        int4 d = d4[q];
        int p;
        p = atomicAdd(&lcur[d.x >> BSH], 1); ebuf[p] = (s.x << BSH) | (d.x & BMASK);
        p = atomicAdd(&lcur[d.y >> BSH], 1); ebuf[p] = (s.y << BSH) | (d.y & BMASK);
        p = atomicAdd(&lcur[d.z >> BSH], 1); ebuf[p] = (s.z << BSH) | (d.z & BMASK);
        p = atomicAdd(&lcur[d.w >> BSH], 1); ebuf[p] = (s.w << BSH) | (d.w & BMASK);
    }
}

__global__ __launch_bounds__(256) void k_bsort(
        const int* __restrict__ ebuf, const int* __restrict__ bucket_base,
        int* __restrict__ sorted_src, int* __restrict__ rowstart) {
    __shared__ int ein[MAXB];
    __shared__ int eout[MAXB];
    __shared__ int hist[128];
    __shared__ int sc[128];
    __shared__ int cursor[128];
    int tid = threadIdx.x, B = blockIdx.x;
    int base = bucket_base[B];
    int n = bucket_base[B + 1] - base;
    if (tid < 128) hist[tid] = 0;
    __syncthreads();
    for (int i = tid; i < n; i += 256) {
        int v = ebuf[base + i];
        ein[i] = v;
        atomicAdd(&hist[v & BMASK], 1);
    }
    __syncthreads();
    if (tid < 128) sc[tid] = hist[tid];
    __syncthreads();
    for (int off = 1; off < 128; off <<= 1) {
        int u = 0;
        if (tid < 128 && tid >= off) u = sc[tid - off];
        __syncthreads();
        if (tid < 128) sc[tid] += u;
        __syncthreads();
    }
    if (tid < 128) {
        int ex = sc[tid] - hist[tid];
        cursor[tid] = ex;
        int node = B * 128 + tid;
        if (node < N_NODES) rowstart[node] = base + ex;
    }
    __syncthreads();
    for (int i = tid; i < n; i += 256) {
        int v = ein[i];
        int p = atomicAdd(&cursor[v & BMASK], 1);
        eout[p] = v >> BSH;
    }
    __syncthreads();
    for (int i = tid; i < n; i += 256) sorted_src[base + i] = eout[i];
}

// ---------------- Layer 1 GEMM: feat1 = x @ W1 (fp16 out), fused el1/er1 ----------------

__global__ __launch_bounds__(256) void k_gemm1(
        const float* __restrict__ x, const float* __restrict__ W1,
        const float* __restrict__ al1, const float* __restrict__ ar1,
        __half* __restrict__ feat1h, float* __restrict__ el1, float* __restrict__ er1) {
    __shared__ float xs[16 * 128];   // [kk][node] transposed x tile, 8 KB
    __shared__ float ws[16 * 128];   // [kk][col]  native W1 tile,   8 KB
    int tid = threadIdx.x;
    int nb = blockIdx.x * 128;
    int ct = tid & 15;               // col-thread: cols ct*8 .. ct*8+7
    int nt = tid >> 4;               // node-thread: nodes nt*8 .. nt*8+7

    float acc[8][8];
    #pragma unroll
    for (int n = 0; n < 8; n++)
        #pragma unroll
        for (int c = 0; c < 8; c++) acc[n][c] = 0.f;

    int lnode = tid & 127;
    int kg = tid >> 7;               // 0/1: which 8 of the 16 k's this thread stages
    int gnode = nb + lnode; if (gnode >= N_NODES) gnode = N_NODES - 1;
    const float4* xrow = (const float4*)(x + (size_t)gnode * FIN);
    const float4* W14 = (const float4*)W1;

    for (int k0 = 0; k0 < FIN; k0 += 16) {
        float4 a0 = xrow[(k0 >> 2) + kg * 2];
        float4 a1 = xrow[(k0 >> 2) + kg * 2 + 1];
        float4 w0 = W14[(size_t)k0 * 32 + tid];
        float4 w1 = W14[(size_t)k0 * 32 + tid + 256];
        __syncthreads();
        int kb = kg * 8;
        xs[(kb + 0) * 128 + lnode] = a0.x;
        xs[(kb + 1) * 128 + lnode] = a0.y;
        xs[(kb + 2) * 128 + lnode] = a0.z;
        xs[(kb + 3) * 128 + lnode] = a0.w;
        xs[(kb + 4) * 128 + lnode] = a1.x;
        xs[(kb + 5) * 128 + lnode] = a1.y;
        xs[(kb + 6) * 128 + lnode] = a1.z;
        xs[(kb + 7) * 128 + lnode] = a1.w;
        ((float4*)ws)[tid] = w0;
        ((float4*)ws)[tid + 256] = w1;
        __syncthreads();
        #pragma unroll
        for (int kk = 0; kk < 16; kk++) {
            float4 xa = ((const float4*)xs)[kk * 32 + nt * 2];
            float4 xb = ((const float4*)xs)[kk * 32 + nt * 2 + 1];
            float4 wa = ((const float4*)ws)[kk * 32 + ct * 2];
            float4 wb = ((const float4*)ws)[kk * 32 + ct * 2 + 1];
            float xn[8] = {xa.x, xa.y, xa.z, xa.w, xb.x, xb.y, xb.z, xb.w};
            float wc[8] = {wa.x, wa.y, wa.z, wa.w, wb.x, wb.y, wb.z, wb.w};
            #pragma unroll
            for (int n = 0; n < 8; n++)
                #pragma unroll
                for (int c = 0; c < 8; c++)
                    acc[n][c] += xn[n] * wc[c];
        }
    }

    float alv[8], arv[8];
    #pragma unroll
    for (int c = 0; c < 8; c++) { alv[c] = al1[ct * 8 + c]; arv[c] = ar1[ct * 8 + c]; }
    int head = ct >> 2;
    #pragma unroll
    for (int n = 0; n < 8; n++) {
        int node = nb + nt * 8 + n;
        bool ok = node < N_NODES;
        if (ok) {
            __half2 ph[4];
            #pragma unroll
            for (int c2 = 0; c2 < 4; c2++)
                ph[c2] = __floats2half2_rn(acc[n][2 * c2], acc[n][2 * c2 + 1]);
            *(float4*)(feat1h + (size_t)node * HD + ct * 8) = *(float4*)ph;
        }
        float pl = 0.f, pr = 0.f;
        #pragma unroll
        for (int c = 0; c < 8; c++) { pl += acc[n][c] * alv[c]; pr += acc[n][c] * arv[c]; }
        pl += __shfl_xor(pl, 1); pl += __shfl_xor(pl, 2);
        pr += __shfl_xor(pr, 1); pr += __shfl_xor(pr, 2);
        if (ok && (ct & 3) == 0) {
            el1[node * 4 + head] = pl;
            er1[node * 4 + head] = pr;
        }
    }
}

// ---------------- Layer 1 aggregation: wave per dst, 4 edges x 16 col-lanes ----------------

__global__ __launch_bounds__(256) void k_agg1(
        const int* __restrict__ rowstart, const int* __restrict__ sorted_src,
        const float* __restrict__ el1, const float* __restrict__ er1,
        const __half* __restrict__ feat1h, const float* __restrict__ b1,
        float* __restrict__ h) {
    int tid = threadIdx.x;
    int d = blockIdx.x * 4 + (tid >> 6);   // 50000 % 4 == 0
    int lane = tid & 63;
    int eg = lane >> 4;                    // edge group 0..3
    int cl = lane & 15;                    // col-lane: cols 8*cl..8*cl+7
    int head = cl >> 2;
    float er = er1[d * 4 + head];
    int start = rowstart[d], end = rowstart[d + 1];
    float acc[8];
    #pragma unroll
    for (int k = 0; k < 8; k++) acc[k] = 0.f;
    float wsum = 0.f;

    for (int i = start; i < end; i += 8) {
        int e0 = i + eg, e1 = i + 4 + eg;
        bool ok0 = e0 < end, ok1 = e1 < end;
        int e0c = ok0 ? e0 : end - 1;
        int e1c = ok1 ? e1 : end - 1;
        int s0 = sorted_src[e0c];
        int s1 = sorted_src[e1c];
        float el0v = el1[s0 * 4 + head];
        float el1v = el1[s1 * 4 + head];
        float4 r0 = *(const float4*)(feat1h + (size_t)s0 * HD + cl * 8);
        float4 r1 = *(const float4*)(feat1h + (size_t)s1 * HD + cl * 8);
        float w0 = ok0 ? lexp(el0v + er) : 0.f;
        float w1 = ok1 ? lexp(el1v + er) : 0.f;
        const __half2* p0 = (const __half2*)&r0;
        const __half2* p1 = (const __half2*)&r1;
        #pragma unroll
        for (int q = 0; q < 4; q++) {
            float2 f0 = __half22float2(p0[q]);
            float2 f1 = __half22float2(p1[q]);
            acc[2 * q]     += w0 * f0.x + w1 * f1.x;
            acc[2 * q + 1] += w0 * f0.y + w1 * f1.y;
        }
        wsum += w0 + w1;
    }
    #pragma unroll
    for (int k = 0; k < 8; k++) {
        acc[k] += __shfl_xor(acc[k], 16);
        acc[k] += __shfl_xor(acc[k], 32);
    }
    wsum += __shfl_xor(wsum, 16);
    wsum += __shfl_xor(wsum, 32);
    if (eg == 0) {
        float inv = 1.f / fmaxf(wsum, 1e-9f);
        float v[8];
        #pragma unroll
        for (int k = 0; k < 8; k++) v[k] = elu1(acc[k] * inv + b1[cl * 8 + k]);
        float4* hp = (float4*)(h + (size_t)d * HD + cl * 8);
        hp[0] = make_float4(v[0], v[1], v[2], v[3]);
        hp[1] = make_float4(v[4], v[5], v[6], v[7]);
    }
}

// ---------------- Layer 2 GEMM: feat2 = h @ W2, fused el2/er2 ----------------

__global__ __launch_bounds__(256) void k_gemm2(
        const float* __restrict__ h, const float* __restrict__ W2,
        const float* __restrict__ al2, const float* __restrict__ ar2,
        float* __restrict__ feat2, float* __restrict__ el2, float* __restrict__ er2) {
    __shared__ float hs[16 * 132];
    __shared__ float w2t[16 * 132];
    int tid = threadIdx.x;
    int nb = blockIdx.x * 16;  // 50000 % 16 == 0
    for (int idx = tid; idx < 512; idx += 256) {
        int row = idx >> 5, kk = idx & 31;
        ((float4*)(hs + row * 132))[kk] = ((const float4*)h)[(size_t)(nb + row) * 32 + kk];
    }
    for (int idx = tid; idx < 2048; idx += 256) {
        int k = idx >> 4, c = idx & 15;
        w2t[c * 132 + k] = W2[idx];
    }
    __syncthreads();
    int nl = tid >> 4, col = tid & 15;
    const float4* hv = (const float4*)(hs + nl * 132);
    const float4* wv = (const float4*)(w2t + col * 132);
    float acc = 0.f;
    #pragma unroll
    for (int kk = 0; kk < 32; kk++) {
        float4 a = hv[kk], w = wv[kk];
        acc += a.x * w.x + a.y * w.y + a.z * w.z + a.w * w.w;
    }
    int node = nb + nl;
    feat2[node * 16 + col] = acc;
    float pl = acc * al2[col], pr = acc * ar2[col];
    #pragma unroll
    for (int m = 8; m >= 1; m >>= 1) {
        pl += __shfl_xor(pl, m);
        pr += __shfl_xor(pr, m);
    }
    if (col == 0) { el2[node] = pl; er2[node] = pr; }
}

// ---------------- Layer 2 aggregation: wave per dst, 16 edges x 4 col-lanes ----------------

__global__ __launch_bounds__(256) void k_agg2(
        const int* __restrict__ rowstart, const int* __restrict__ sorted_src,
        const float* __restrict__ el2, const float* __restrict__ er2,
        const float* __restrict__ feat2, const float* __restrict__ b2,
        float* __restrict__ out) {
    int tid = threadIdx.x;
    int d = blockIdx.x * 4 + (tid >> 6);   // 50000 % 4 == 0
    int lane = tid & 63;
    int eg = lane >> 2;                    // edge group 0..15
    int cq = lane & 3;                     // cols 4*cq..4*cq+3
    float er = er2[d];
    int start = rowstart[d], end = rowstart[d + 1];
    float4 acc = make_float4(0.f, 0.f, 0.f, 0.f);
    float wsum = 0.f;
    for (int i = start; i < end; i += 16) {
        int e = i + eg;
        bool ok = e < end;
        int ec = ok ? e : end - 1;
        int s = sorted_src[ec];
        float elv = el2[s];
        float4 f = ((const float4*)feat2)[(size_t)s * 4 + cq];
        float ev = elv + er;
        float wr = __expf(ev > 0.f ? ev : NEG * ev);
        float w = ok ? wr : 0.f;
        acc.x += w * f.x; acc.y += w * f.y; acc.z += w * f.z; acc.w += w * f.w;
        wsum += w;
    }
    #pragma unroll
    for (int m = 4; m <= 32; m <<= 1) {
        acc.x += __shfl_xor(acc.x, m);
        acc.y += __shfl_xor(acc.y, m);
        acc.z += __shfl_xor(acc.z, m);
        acc.w += __shfl_xor(acc.w, m);
        wsum  += __shfl_xor(wsum, m);
    }
    if (lane < 4) {
        float inv = 1.f / fmaxf(wsum, 1e-9f);
        float4 bv = ((const float4*)b2)[cq];
        float4 o = make_float4(acc.x * inv + bv.x, acc.y * inv + bv.y,
                               acc.z * inv + bv.z, acc.w * inv + bv.w);
        ((float4*)out)[(size_t)d * 4 + cq] = o;
    }
}

// ---------------- launch ----------------

extern "C" void kernel_launch(void* const* d_in, const int* in_sizes, int n_in,
                              void* d_out, int out_size, void* d_ws, size_t ws_size,
                              hipStream_t stream) {
    const float* x   = (const float*)d_in[0];
    const int*   src = (const int*)d_in[1];
    const int*   dst = (const int*)d_in[2];
    const float* W1  = (const float*)d_in[3];
    const float* b1  = (const float*)d_in[4];
    const float* al1 = (const float*)d_in[5];
    const float* ar1 = (const float*)d_in[6];
    const float* W2  = (const float*)d_in[7];
    const float* b2  = (const float*)d_in[8];
    const float* al2 = (const float*)d_in[9];
    const float* ar2 = (const float*)d_in[10];
    float* out = (float*)d_out;

    char* ws = (char*)d_ws;
    size_t off = 0;
    auto alloc = [&](size_t bytes) -> char* {
        char* p = ws + off;
        off += (bytes + 255) & ~(size_t)255;
        return p;
    };
    __half* feat1h    = (__half*)alloc((size_t)N_NODES * HD * 2);
    float* h          = (float*)alloc((size_t)N_NODES * HD * 4);
    float* el1        = (float*)alloc((size_t)N_NODES * 4 * 4);
    float* er1        = (float*)alloc((size_t)N_NODES * 4 * 4);
    float* feat2      = (float*)alloc((size_t)N_NODES * C2 * 4);
    float* el2        = (float*)alloc((size_t)N_NODES * 4);
    float* er2        = (float*)alloc((size_t)N_NODES * 4);
    int*   ghist      = (int*)alloc((size_t)NBUCK * NBLK * 4);
    int*   bucket_base= (int*)alloc((size_t)(NBUCK + 1) * 4);
    int*   rowstart   = (int*)alloc((size_t)(N_NODES + 1) * 4);
    int*   ebuf       = (int*)alloc((size_t)N_EDGES * 4);
    int*   sorted_src = (int*)alloc((size_t)N_EDGES * 4);

    k_bhist<<<NBLK, 256, 0, stream>>>(dst, ghist);
    k_bscan<<<1, 512, 0, stream>>>(ghist, bucket_base, rowstart);
    k_bscatter<<<NBLK, 256, 0, stream>>>(src, dst, ghist, bucket_base, ebuf);
    k_bsort<<<NBUCK, 256, 0, stream>>>(ebuf, bucket_base, sorted_src, rowstart);
    k_gemm1<<<(N_NODES + 127) / 128, 256, 0, stream>>>(x, W1, al1, ar1, feat1h, el1, er1);
    k_agg1<<<N_NODES / 4, 256, 0, stream>>>(rowstart, sorted_src, el1, er1, feat1h, b1, h);
    k_gemm2<<<N_NODES / 16, 256, 0, stream>>>(h, W2, al2, ar2, feat2, el2, er2);
    k_agg2<<<N_NODES / 4, 256, 0, stream>>>(rowstart, sorted_src, el2, er2, feat2, b2, out);
}

// Round 7
// 326.292 us; speedup vs baseline: 1.4077x; 1.0119x over previous
//
#include <hip/hip_runtime.h>
#include <hip/hip_fp16.h>

#define N_NODES 50000
#define N_EDGES 1600000
#define FIN 256
#define HD 128          // HEADS*HIDDEN
#define NHEADS 4
#define C2 16           // NUM_CLASSES
#define NEG 0.2f

// bucketed counting-sort CSR build
#define EBLK 4096
#define NBLK 391        // ceil(N_EDGES/EBLK)
#define NBUCK 391       // ceil(N_NODES/128)
#define BSH 7
#define BMASK 127
#define MAXB 5120       // bucket capacity: mean 4096, sigma ~64 -> +16 sigma

__device__ __forceinline__ float elu1(float x) { return x > 0.f ? x : __expf(x) - 1.f; }
__device__ __forceinline__ float lexp(float e) { return __expf(e > 0.f ? e : NEG * e); }

// ---------------- CSR build: bucketed counting sort ----------------

__global__ __launch_bounds__(256) void k_bhist(const int* __restrict__ dst,
                                               int* __restrict__ ghist) {
    __shared__ int lh[NBUCK];
    int tid = threadIdx.x, b = blockIdx.x;
    for (int t = tid; t < NBUCK; t += 256) lh[t] = 0;
    __syncthreads();
    int base = b * EBLK;
    int nq = (min(EBLK, N_EDGES - base)) >> 2;
    const int4* d4 = (const int4*)(dst + base);
    for (int q = tid; q < nq; q += 256) {
        int4 d = d4[q];
        atomicAdd(&lh[d.x >> BSH], 1);
        atomicAdd(&lh[d.y >> BSH], 1);
        atomicAdd(&lh[d.z >> BSH], 1);
        atomicAdd(&lh[d.w >> BSH], 1);
    }
    __syncthreads();
    for (int t = tid; t < NBUCK; t += 256) ghist[t * NBLK + b] = lh[t];
}

__global__ __launch_bounds__(512) void k_bscan(int* __restrict__ ghist,
                                               int* __restrict__ bucket_base,
                                               int* __restrict__ rowstart) {
    __shared__ int s[512];
    int t = threadIdx.x;
    int run = 0;
    if (t < NBUCK) {
        for (int b = 0; b < NBLK; b++) {
            int v = ghist[t * NBLK + b];
            ghist[t * NBLK + b] = run;   // within-bucket exclusive prefix per block
            run += v;
        }
    }
    s[t] = (t < NBUCK) ? run : 0;
    __syncthreads();
    for (int off = 1; off < 512; off <<= 1) {
        int u = (t >= off) ? s[t - off] : 0;
        __syncthreads();
        s[t] += u;
        __syncthreads();
    }
    if (t < NBUCK) bucket_base[t] = s[t] - run;  // exclusive over buckets
    if (t == 0) { bucket_base[NBUCK] = N_EDGES; rowstart[N_NODES] = N_EDGES; }
}

__global__ __launch_bounds__(256) void k_bscatter(
        const int* __restrict__ src, const int* __restrict__ dst,
        const int* __restrict__ ghist, const int* __restrict__ bucket_base,
        int* __restrict__ ebuf) {
    __shared__ int lcur[NBUCK];
    int tid = threadIdx.x, b = blockIdx.x;
    for (int t = tid; t < NBUCK; t += 256)
        lcur[t] = bucket_base[t] + ghist[t * NBLK + b];
    __syncthreads();
    int base = b * EBLK;
    int nq = (min(EBLK, N_EDGES - base)) >> 2;
    const int4* s4 = (const int4*)(src + base);
    const int4* d4 = (const int4*)(dst + base);
    for (int q = tid; q < nq; q += 256) {
        int4 s = s4[q];
        int4 d = d4[q];
        int p;
        p = atomicAdd(&lcur[d.x >> BSH], 1); ebuf[p] = (s.x << BSH) | (d.x & BMASK);
        p = atomicAdd(&lcur[d.y >> BSH], 1); ebuf[p] = (s.y << BSH) | (d.y & BMASK);
        p = atomicAdd(&lcur[d.z >> BSH], 1); ebuf[p] = (s.z << BSH) | (d.z & BMASK);
        p = atomicAdd(&lcur[d.w >> BSH], 1); ebuf[p] = (s.w << BSH) | (d.w & BMASK);
    }
}

__global__ __launch_bounds__(256) void k_bsort(
        const int* __restrict__ ebuf, const int* __restrict__ bucket_base,
        int* __restrict__ sorted_src, int* __restrict__ rowstart) {
    __shared__ int ein[MAXB];
    __shared__ int eout[MAXB];
    __shared__ int hist[128];
    __shared__ int sc[128];
    __shared__ int cursor[128];
    int tid = threadIdx.x, B = blockIdx.x;
    int base = bucket_base[B];
    int n = bucket_base[B + 1] - base;
    if (tid < 128) hist[tid] = 0;
    __syncthreads();
    for (int i = tid; i < n; i += 256) {
        int v = ebuf[base + i];
        ein[i] = v;
        atomicAdd(&hist[v & BMASK], 1);
    }
    __syncthreads();
    if (tid < 128) sc[tid] = hist[tid];
    __syncthreads();
    for (int off = 1; off < 128; off <<= 1) {
        int u = 0;
        if (tid < 128 && tid >= off) u = sc[tid - off];
        __syncthreads();
        if (tid < 128) sc[tid] += u;
        __syncthreads();
    }
    if (tid < 128) {
        int ex = sc[tid] - hist[tid];
        cursor[tid] = ex;
        int node = B * 128 + tid;
        if (node < N_NODES) rowstart[node] = base + ex;
    }
    __syncthreads();
    for (int i = tid; i < n; i += 256) {
        int v = ein[i];
        int p = atomicAdd(&cursor[v & BMASK], 1);
        eout[p] = v >> BSH;
    }
    __syncthreads();
    for (int i = tid; i < n; i += 256) sorted_src[base + i] = eout[i];
}

// ---------------- Layer 1 GEMM: feat1 = x @ W1 (fp16 out), fused el1/er1 ----------------
// BM=64 x BN=128 x BK=16, 256 threads, 4x8 register tile.
// Thread ct owns cols [4ct..4ct+3] (group A) and [64+4ct..64+4ct+3] (group B)
// so B-operand LDS reads are 16 consecutive float4s -> 2 lanes/bank (free).

__global__ __launch_bounds__(256) void k_gemm1(
        const float* __restrict__ x, const float* __restrict__ W1,
        const float* __restrict__ al1, const float* __restrict__ ar1,
        __half* __restrict__ feat1h, float* __restrict__ el1, float* __restrict__ er1) {
    __shared__ float xs[16 * 64];    // [kk][node], 4 KB
    __shared__ float ws[16 * 128];   // [kk][col],  8 KB
    int tid = threadIdx.x;
    int nb = blockIdx.x * 64;
    int ct = tid & 15;               // col-thread
    int nt = tid >> 4;               // 0..15: nodes nt*4..nt*4+3

    float acc[4][8];
    #pragma unroll
    for (int n = 0; n < 4; n++)
        #pragma unroll
        for (int c = 0; c < 8; c++) acc[n][c] = 0.f;

    int lnode = tid & 63;
    int kg = tid >> 6;               // 0..3: which 4 of the 16 k's this thread stages
    int gnode = nb + lnode; if (gnode >= N_NODES) gnode = N_NODES - 1;
    const float4* xrow = (const float4*)(x + (size_t)gnode * FIN);
    const float4* W14 = (const float4*)W1;

    for (int k0 = 0; k0 < FIN; k0 += 16) {
        float4 a0 = xrow[(k0 >> 2) + kg];
        float4 w0 = W14[(size_t)k0 * 32 + tid];
        float4 w1 = W14[(size_t)k0 * 32 + tid + 256];
        __syncthreads();             // previous tile's compute done before overwrite
        int kb = kg * 4;
        xs[(kb + 0) * 64 + lnode] = a0.x;
        xs[(kb + 1) * 64 + lnode] = a0.y;
        xs[(kb + 2) * 64 + lnode] = a0.z;
        xs[(kb + 3) * 64 + lnode] = a0.w;
        ((float4*)ws)[tid] = w0;
        ((float4*)ws)[tid + 256] = w1;
        __syncthreads();
        #pragma unroll
        for (int kk = 0; kk < 16; kk++) {
            float4 xa = ((const float4*)xs)[kk * 16 + nt];        // broadcast per nt
            float4 wa = ((const float4*)ws)[kk * 32 + ct];        // cols 4ct..4ct+3
            float4 wb = ((const float4*)ws)[kk * 32 + 16 + ct];   // cols 64+4ct..+3
            float xn[4] = {xa.x, xa.y, xa.z, xa.w};
            float wc[8] = {wa.x, wa.y, wa.z, wa.w, wb.x, wb.y, wb.z, wb.w};
            #pragma unroll
            for (int n = 0; n < 4; n++)
                #pragma unroll
                for (int c = 0; c < 8; c++)
                    acc[n][c] += xn[n] * wc[c];
        }
    }

    // epilogue: fp16 feat1 stores + fused el/er (two heads per thread)
    float alvA[4], arvA[4], alvB[4], arvB[4];
    #pragma unroll
    for (int j = 0; j < 4; j++) {
        alvA[j] = al1[4 * ct + j];      arvA[j] = ar1[4 * ct + j];
        alvB[j] = al1[64 + 4 * ct + j]; arvB[j] = ar1[64 + 4 * ct + j];
    }
    int headA = ct >> 3;          // 0 or 1
    int headB = 2 + (ct >> 3);    // 2 or 3
    #pragma unroll
    for (int n = 0; n < 4; n++) {
        int node = nb + nt * 4 + n;
        bool ok = node < N_NODES;
        if (ok) {
            __half2 ha[2], hb[2];
            ha[0] = __floats2half2_rn(acc[n][0], acc[n][1]);
            ha[1] = __floats2half2_rn(acc[n][2], acc[n][3]);
            hb[0] = __floats2half2_rn(acc[n][4], acc[n][5]);
            hb[1] = __floats2half2_rn(acc[n][6], acc[n][7]);
            *(float2*)(feat1h + (size_t)node * HD + 4 * ct) = *(float2*)ha;
            *(float2*)(feat1h + (size_t)node * HD + 64 + 4 * ct) = *(float2*)hb;
        }
        float plA = 0.f, prA = 0.f, plB = 0.f, prB = 0.f;
        #pragma unroll
        for (int j = 0; j < 4; j++) {
            plA += acc[n][j] * alvA[j];     prA += acc[n][j] * arvA[j];
            plB += acc[n][4 + j] * alvB[j]; prB += acc[n][4 + j] * arvB[j];
        }
        // reduce across the 8 ct-threads of each head (ct bits 0..2 == lane bits 0..2)
        #pragma unroll
        for (int m = 1; m <= 4; m <<= 1) {
            plA += __shfl_xor(plA, m); prA += __shfl_xor(prA, m);
            plB += __shfl_xor(plB, m); prB += __shfl_xor(prB, m);
        }
        if (ok && (ct & 7) == 0) {
            el1[node * 4 + headA] = plA; er1[node * 4 + headA] = prA;
            el1[node * 4 + headB] = plB; er1[node * 4 + headB] = prB;
        }
    }
}

// ---------------- Layer 1 aggregation: wave per dst, 4 edges x 16 col-lanes ----------------

__global__ __launch_bounds__(256) void k_agg1(
        const int* __restrict__ rowstart, const int* __restrict__ sorted_src,
        const float* __restrict__ el1, const float* __restrict__ er1,
        const __half* __restrict__ feat1h, const float* __restrict__ b1,
        float* __restrict__ h) {
    int tid = threadIdx.x;
    int d = blockIdx.x * 4 + (tid >> 6);   // 50000 % 4 == 0
    int lane = tid & 63;
    int eg = lane >> 4;                    // edge group 0..3
    int cl = lane & 15;                    // col-lane: cols 8*cl..8*cl+7
    int head = cl >> 2;
    float er = er1[d * 4 + head];
    int start = rowstart[d], end = rowstart[d + 1];
    float acc[8];
    #pragma unroll
    for (int k = 0; k < 8; k++) acc[k] = 0.f;
    float wsum = 0.f;

    for (int i = start; i < end; i += 8) {
        int e0 = i + eg, e1 = i + 4 + eg;
        bool ok0 = e0 < end, ok1 = e1 < end;
        int e0c = ok0 ? e0 : end - 1;
        int e1c = ok1 ? e1 : end - 1;
        int s0 = sorted_src[e0c];
        int s1 = sorted_src[e1c];
        float el0v = el1[s0 * 4 + head];
        float el1v = el1[s1 * 4 + head];
        float4 r0 = *(const float4*)(feat1h + (size_t)s0 * HD + cl * 8);
        float4 r1 = *(const float4*)(feat1h + (size_t)s1 * HD + cl * 8);
        float w0 = ok0 ? lexp(el0v + er) : 0.f;
        float w1 = ok1 ? lexp(el1v + er) : 0.f;
        const __half2* p0 = (const __half2*)&r0;
        const __half2* p1 = (const __half2*)&r1;
        #pragma unroll
        for (int q = 0; q < 4; q++) {
            float2 f0 = __half22float2(p0[q]);
            float2 f1 = __half22float2(p1[q]);
            acc[2 * q]     += w0 * f0.x + w1 * f1.x;
            acc[2 * q + 1] += w0 * f0.y + w1 * f1.y;
        }
        wsum += w0 + w1;
    }
    #pragma unroll
    for (int k = 0; k < 8; k++) {
        acc[k] += __shfl_xor(acc[k], 16);
        acc[k] += __shfl_xor(acc[k], 32);
    }
    wsum += __shfl_xor(wsum, 16);
    wsum += __shfl_xor(wsum, 32);
    if (eg == 0) {
        float inv = 1.f / fmaxf(wsum, 1e-9f);
        float v[8];
        #pragma unroll
        for (int k = 0; k < 8; k++) v[k] = elu1(acc[k] * inv + b1[cl * 8 + k]);
        float4* hp = (float4*)(h + (size_t)d * HD + cl * 8);
        hp[0] = make_float4(v[0], v[1], v[2], v[3]);
        hp[1] = make_float4(v[4], v[5], v[6], v[7]);
    }
}

// ---------------- Layer 2 GEMM: feat2 = h @ W2, fused el2/er2 ----------------

__global__ __launch_bounds__(256) void k_gemm2(
        const float* __restrict__ h, const float* __restrict__ W2,
        const float* __restrict__ al2, const float* __restrict__ ar2,
        float* __restrict__ feat2, float* __restrict__ el2, float* __restrict__ er2) {
    __shared__ float hs[16 * 132];
    __shared__ float w2t[16 * 132];
    int tid = threadIdx.x;
    int nb = blockIdx.x * 16;  // 50000 % 16 == 0
    for (int idx = tid; idx < 512; idx += 256) {
        int row = idx >> 5, kk = idx & 31;
        ((float4*)(hs + row * 132))[kk] = ((const float4*)h)[(size_t)(nb + row) * 32 + kk];
    }
    for (int idx = tid; idx < 2048; idx += 256) {
        int k = idx >> 4, c = idx & 15;
        w2t[c * 132 + k] = W2[idx];
    }
    __syncthreads();
    int nl = tid >> 4, col = tid & 15;
    const float4* hv = (const float4*)(hs + nl * 132);
    const float4* wv = (const float4*)(w2t + col * 132);
    float acc = 0.f;
    #pragma unroll
    for (int kk = 0; kk < 32; kk++) {
        float4 a = hv[kk], w = wv[kk];
        acc += a.x * w.x + a.y * w.y + a.z * w.z + a.w * w.w;
    }
    int node = nb + nl;
    feat2[node * 16 + col] = acc;
    float pl = acc * al2[col], pr = acc * ar2[col];
    #pragma unroll
    for (int m = 8; m >= 1; m >>= 1) {
        pl += __shfl_xor(pl, m);
        pr += __shfl_xor(pr, m);
    }
    if (col == 0) { el2[node] = pl; er2[node] = pr; }
}

// ---------------- Layer 2 aggregation: wave per dst, 16 edges x 4 col-lanes ----------------

__global__ __launch_bounds__(256) void k_agg2(
        const int* __restrict__ rowstart, const int* __restrict__ sorted_src,
        const float* __restrict__ el2, const float* __restrict__ er2,
        const float* __restrict__ feat2, const float* __restrict__ b2,
        float* __restrict__ out) {
    int tid = threadIdx.x;
    int d = blockIdx.x * 4 + (tid >> 6);   // 50000 % 4 == 0
    int lane = tid & 63;
    int eg = lane >> 2;                    // edge group 0..15
    int cq = lane & 3;                     // cols 4*cq..4*cq+3
    float er = er2[d];
    int start = rowstart[d], end = rowstart[d + 1];
    float4 acc = make_float4(0.f, 0.f, 0.f, 0.f);
    float wsum = 0.f;
    for (int i = start; i < end; i += 16) {
        int e = i + eg;
        bool ok = e < end;
        int ec = ok ? e : end - 1;
        int s = sorted_src[ec];
        float elv = el2[s];
        float4 f = ((const float4*)feat2)[(size_t)s * 4 + cq];
        float ev = elv + er;
        float wr = __expf(ev > 0.f ? ev : NEG * ev);
        float w = ok ? wr : 0.f;
        acc.x += w * f.x; acc.y += w * f.y; acc.z += w * f.z; acc.w += w * f.w;
        wsum += w;
    }
    #pragma unroll
    for (int m = 4; m <= 32; m <<= 1) {
        acc.x += __shfl_xor(acc.x, m);
        acc.y += __shfl_xor(acc.y, m);
        acc.z += __shfl_xor(acc.z, m);
        acc.w += __shfl_xor(acc.w, m);
        wsum  += __shfl_xor(wsum, m);
    }
    if (lane < 4) {
        float inv = 1.f / fmaxf(wsum, 1e-9f);
        float4 bv = ((const float4*)b2)[cq];
        float4 o = make_float4(acc.x * inv + bv.x, acc.y * inv + bv.y,
                               acc.z * inv + bv.z, acc.w * inv + bv.w);
        ((float4*)out)[(size_t)d * 4 + cq] = o;
    }
}

// ---------------- launch ----------------

extern "C" void kernel_launch(void* const* d_in, const int* in_sizes, int n_in,
                              void* d_out, int out_size, void* d_ws, size_t ws_size,
                              hipStream_t stream) {
    const float* x   = (const float*)d_in[0];
    const int*   src = (const int*)d_in[1];
    const int*   dst = (const int*)d_in[2];
    const float* W1  = (const float*)d_in[3];
    const float* b1  = (const float*)d_in[4];
    const float* al1 = (const float*)d_in[5];
    const float* ar1 = (const float*)d_in[6];
    const float* W2  = (const float*)d_in[7];
    const float* b2  = (const float*)d_in[8];
    const float* al2 = (const float*)d_in[9];
    const float* ar2 = (const float*)d_in[10];
    float* out = (float*)d_out;

    char* ws = (char*)d_ws;
    size_t off = 0;
    auto alloc = [&](size_t bytes) -> char* {
        char* p = ws + off;
        off += (bytes + 255) & ~(size_t)255;
        return p;
    };
    __half* feat1h    = (__half*)alloc((size_t)N_NODES * HD * 2);
    float* h          = (float*)alloc((size_t)N_NODES * HD * 4);
    float* el1        = (float*)alloc((size_t)N_NODES * 4 * 4);
    float* er1        = (float*)alloc((size_t)N_NODES * 4 * 4);
    float* feat2      = (float*)alloc((size_t)N_NODES * C2 * 4);
    float* el2        = (float*)alloc((size_t)N_NODES * 4);
    float* er2        = (float*)alloc((size_t)N_NODES * 4);
    int*   ghist      = (int*)alloc((size_t)NBUCK * NBLK * 4);
    int*   bucket_base= (int*)alloc((size_t)(NBUCK + 1) * 4);
    int*   rowstart   = (int*)alloc((size_t)(N_NODES + 1) * 4);
    int*   ebuf       = (int*)alloc((size_t)N_EDGES * 4);
    int*   sorted_src = (int*)alloc((size_t)N_EDGES * 4);

    k_bhist<<<NBLK, 256, 0, stream>>>(dst, ghist);
    k_bscan<<<1, 512, 0, stream>>>(ghist, bucket_base, rowstart);
    k_bscatter<<<NBLK, 256, 0, stream>>>(src, dst, ghist, bucket_base, ebuf);
    k_bsort<<<NBUCK, 256, 0, stream>>>(ebuf, bucket_base, sorted_src, rowstart);
    k_gemm1<<<(N_NODES + 63) / 64, 256, 0, stream>>>(x, W1, al1, ar1, feat1h, el1, er1);
    k_agg1<<<N_NODES / 4, 256, 0, stream>>>(rowstart, sorted_src, el1, er1, feat1h, b1, h);
    k_gemm2<<<N_NODES / 16, 256, 0, stream>>>(h, W2, al2, ar2, feat2, el2, er2);
    k_agg2<<<N_NODES / 4, 256, 0, stream>>>(rowstart, sorted_src, el2, er2, feat2, b2, out);
}

// Round 8
// 274.232 us; speedup vs baseline: 1.6750x; 1.1898x over previous
//
#include <hip/hip_runtime.h>
#include <hip/hip_fp16.h>

#define N_NODES 50000
#define N_EDGES 1600000
#define FIN 256
#define HD 128          // HEADS*HIDDEN
#define NHEADS 4
#define C2 16           // NUM_CLASSES
#define NEG 0.2f

// bucketed counting-sort CSR build
#define EBLK 4096
#define NBLK 391        // ceil(N_EDGES/EBLK)
#define NBUCK 391       // ceil(N_NODES/128)
#define BSH 7
#define BMASK 127
#define MAXB 5120       // bucket capacity: mean 4096, sigma ~64 -> +16 sigma

__device__ __forceinline__ float elu1(float x) { return x > 0.f ? x : __expf(x) - 1.f; }
__device__ __forceinline__ float lexp(float e) { return __expf(e > 0.f ? e : NEG * e); }

// ---------------- CSR build: bucketed counting sort ----------------

__global__ __launch_bounds__(256) void k_bhist(const int* __restrict__ dst,
                                               int* __restrict__ ghist) {
    __shared__ int lh[NBUCK];
    int tid = threadIdx.x, b = blockIdx.x;
    for (int t = tid; t < NBUCK; t += 256) lh[t] = 0;
    __syncthreads();
    int base = b * EBLK;
    int nq = (min(EBLK, N_EDGES - base)) >> 2;
    const int4* d4 = (const int4*)(dst + base);
    for (int q = tid; q < nq; q += 256) {
        int4 d = d4[q];
        atomicAdd(&lh[d.x >> BSH], 1);
        atomicAdd(&lh[d.y >> BSH], 1);
        atomicAdd(&lh[d.z >> BSH], 1);
        atomicAdd(&lh[d.w >> BSH], 1);
    }
    __syncthreads();
    for (int t = tid; t < NBUCK; t += 256) ghist[t * NBLK + b] = lh[t];
}

// per-bucket scan over blocks: one block per bucket, contiguous coalesced row.
__global__ __launch_bounds__(256) void k_bscan1(int* __restrict__ ghist,
                                                int* __restrict__ bucket_tot) {
    __shared__ int s[256];
    int B = blockIdx.x, t = threadIdx.x;
    int* row = ghist + (size_t)B * NBLK;
    int i0 = 2 * t, i1 = 2 * t + 1;
    int a0 = (i0 < NBLK) ? row[i0] : 0;
    int a1 = (i1 < NBLK) ? row[i1] : 0;
    int pair = a0 + a1;
    s[t] = pair;
    __syncthreads();
    for (int off = 1; off < 256; off <<= 1) {
        int u = (t >= off) ? s[t - off] : 0;
        __syncthreads();
        s[t] += u;
        __syncthreads();
    }
    int excl = s[t] - pair;   // exclusive over pairs
    if (i0 < NBLK) row[i0] = excl;
    if (i1 < NBLK) row[i1] = excl + a0;
    if (t == 255) bucket_tot[B] = s[255];
}

// scan over buckets
__global__ __launch_bounds__(512) void k_bscan2(const int* __restrict__ bucket_tot,
                                                int* __restrict__ bucket_base,
                                                int* __restrict__ rowstart) {
    __shared__ int s[512];
    int t = threadIdx.x;
    int v = (t < NBUCK) ? bucket_tot[t] : 0;
    s[t] = v;
    __syncthreads();
    for (int off = 1; off < 512; off <<= 1) {
        int u = (t >= off) ? s[t - off] : 0;
        __syncthreads();
        s[t] += u;
        __syncthreads();
    }
    if (t < NBUCK) bucket_base[t] = s[t] - v;  // exclusive
    if (t == 0) { bucket_base[NBUCK] = N_EDGES; rowstart[N_NODES] = N_EDGES; }
}

__global__ __launch_bounds__(256) void k_bscatter(
        const int* __restrict__ src, const int* __restrict__ dst,
        const int* __restrict__ ghist, const int* __restrict__ bucket_base,
        int* __restrict__ ebuf) {
    __shared__ int lcur[NBUCK];
    int tid = threadIdx.x, b = blockIdx.x;
    for (int t = tid; t < NBUCK; t += 256)
        lcur[t] = bucket_base[t] + ghist[t * NBLK + b];
    __syncthreads();
    int base = b * EBLK;
    int nq = (min(EBLK, N_EDGES - base)) >> 2;
    const int4* s4 = (const int4*)(src + base);
    const int4* d4 = (const int4*)(dst + base);
    for (int q = tid; q < nq; q += 256) {
        int4 s = s4[q];
        int4 d = d4[q];
        int p;
        p = atomicAdd(&lcur[d.x >> BSH], 1); ebuf[p] = (s.x << BSH) | (d.x & BMASK);
        p = atomicAdd(&lcur[d.y >> BSH], 1); ebuf[p] = (s.y << BSH) | (d.y & BMASK);
        p = atomicAdd(&lcur[d.z >> BSH], 1); ebuf[p] = (s.z << BSH) | (d.z & BMASK);
        p = atomicAdd(&lcur[d.w >> BSH], 1); ebuf[p] = (s.w << BSH) | (d.w & BMASK);
    }
}

__global__ __launch_bounds__(256) void k_bsort(
        const int* __restrict__ ebuf, const int* __restrict__ bucket_base,
        int* __restrict__ sorted_src, int* __restrict__ rowstart) {
    __shared__ int ein[MAXB];
    __shared__ int eout[MAXB];
    __shared__ int hist[128];
    __shared__ int sc[128];
    __shared__ int cursor[128];
    int tid = threadIdx.x, B = blockIdx.x;
    int base = bucket_base[B];
    int n = bucket_base[B + 1] - base;
    if (tid < 128) hist[tid] = 0;
    __syncthreads();
    for (int i = tid; i < n; i += 256) {
        int v = ebuf[base + i];
        ein[i] = v;
        atomicAdd(&hist[v & BMASK], 1);
    }
    __syncthreads();
    if (tid < 128) sc[tid] = hist[tid];
    __syncthreads();
    for (int off = 1; off < 128; off <<= 1) {
        int u = 0;
        if (tid < 128 && tid >= off) u = sc[tid - off];
        __syncthreads();
        if (tid < 128) sc[tid] += u;
        __syncthreads();
    }
    if (tid < 128) {
        int ex = sc[tid] - hist[tid];
        cursor[tid] = ex;
        int node = B * 128 + tid;
        if (node < N_NODES) rowstart[node] = base + ex;
    }
    __syncthreads();
    for (int i = tid; i < n; i += 256) {
        int v = ein[i];
        int p = atomicAdd(&cursor[v & BMASK], 1);
        eout[p] = v >> BSH;
    }
    __syncthreads();
    for (int i = tid; i < n; i += 256) sorted_src[base + i] = eout[i];
}

// ---------------- Layer 1 GEMM: feat1 = x @ W1 (fp16 out), fused el1/er1 ----------------
// BM=64 x BN=128 x BK=16, 256 threads, 4x8 register tile, conflict-free col map.

__global__ __launch_bounds__(256) void k_gemm1(
        const float* __restrict__ x, const float* __restrict__ W1,
        const float* __restrict__ al1, const float* __restrict__ ar1,
        __half* __restrict__ feat1h, float* __restrict__ el1, float* __restrict__ er1) {
    __shared__ float xs[16 * 64];    // [kk][node], 4 KB
    __shared__ float ws[16 * 128];   // [kk][col],  8 KB
    int tid = threadIdx.x;
    int nb = blockIdx.x * 64;
    int ct = tid & 15;               // col-thread
    int nt = tid >> 4;               // 0..15: nodes nt*4..nt*4+3

    float acc[4][8];
    #pragma unroll
    for (int n = 0; n < 4; n++)
        #pragma unroll
        for (int c = 0; c < 8; c++) acc[n][c] = 0.f;

    int lnode = tid & 63;
    int kg = tid >> 6;               // 0..3: which 4 of the 16 k's this thread stages
    int gnode = nb + lnode; if (gnode >= N_NODES) gnode = N_NODES - 1;
    const float4* xrow = (const float4*)(x + (size_t)gnode * FIN);
    const float4* W14 = (const float4*)W1;

    for (int k0 = 0; k0 < FIN; k0 += 16) {
        float4 a0 = xrow[(k0 >> 2) + kg];
        float4 w0 = W14[(size_t)k0 * 32 + tid];
        float4 w1 = W14[(size_t)k0 * 32 + tid + 256];
        __syncthreads();             // previous tile's compute done before overwrite
        int kb = kg * 4;
        xs[(kb + 0) * 64 + lnode] = a0.x;
        xs[(kb + 1) * 64 + lnode] = a0.y;
        xs[(kb + 2) * 64 + lnode] = a0.z;
        xs[(kb + 3) * 64 + lnode] = a0.w;
        ((float4*)ws)[tid] = w0;
        ((float4*)ws)[tid + 256] = w1;
        __syncthreads();
        #pragma unroll
        for (int kk = 0; kk < 16; kk++) {
            float4 xa = ((const float4*)xs)[kk * 16 + nt];        // broadcast per nt
            float4 wa = ((const float4*)ws)[kk * 32 + ct];        // cols 4ct..4ct+3
            float4 wb = ((const float4*)ws)[kk * 32 + 16 + ct];   // cols 64+4ct..+3
            float xn[4] = {xa.x, xa.y, xa.z, xa.w};
            float wc[8] = {wa.x, wa.y, wa.z, wa.w, wb.x, wb.y, wb.z, wb.w};
            #pragma unroll
            for (int n = 0; n < 4; n++)
                #pragma unroll
                for (int c = 0; c < 8; c++)
                    acc[n][c] += xn[n] * wc[c];
        }
    }

    // epilogue: fp16 feat1 stores + fused el/er (two heads per thread)
    float alvA[4], arvA[4], alvB[4], arvB[4];
    #pragma unroll
    for (int j = 0; j < 4; j++) {
        alvA[j] = al1[4 * ct + j];      arvA[j] = ar1[4 * ct + j];
        alvB[j] = al1[64 + 4 * ct + j]; arvB[j] = ar1[64 + 4 * ct + j];
    }
    int headA = ct >> 3;          // 0 or 1
    int headB = 2 + (ct >> 3);    // 2 or 3
    #pragma unroll
    for (int n = 0; n < 4; n++) {
        int node = nb + nt * 4 + n;
        bool ok = node < N_NODES;
        if (ok) {
            __half2 ha[2], hb[2];
            ha[0] = __floats2half2_rn(acc[n][0], acc[n][1]);
            ha[1] = __floats2half2_rn(acc[n][2], acc[n][3]);
            hb[0] = __floats2half2_rn(acc[n][4], acc[n][5]);
            hb[1] = __floats2half2_rn(acc[n][6], acc[n][7]);
            *(float2*)(feat1h + (size_t)node * HD + 4 * ct) = *(float2*)ha;
            *(float2*)(feat1h + (size_t)node * HD + 64 + 4 * ct) = *(float2*)hb;
        }
        float plA = 0.f, prA = 0.f, plB = 0.f, prB = 0.f;
        #pragma unroll
        for (int j = 0; j < 4; j++) {
            plA += acc[n][j] * alvA[j];     prA += acc[n][j] * arvA[j];
            plB += acc[n][4 + j] * alvB[j]; prB += acc[n][4 + j] * arvB[j];
        }
        #pragma unroll
        for (int m = 1; m <= 4; m <<= 1) {
            plA += __shfl_xor(plA, m); prA += __shfl_xor(prA, m);
            plB += __shfl_xor(plB, m); prB += __shfl_xor(prB, m);
        }
        if (ok && (ct & 7) == 0) {
            el1[node * 4 + headA] = plA; er1[node * 4 + headA] = prA;
            el1[node * 4 + headB] = plB; er1[node * 4 + headB] = prB;
        }
    }
}

// ---------------- Layer 1 aggregation: wave per dst, 4 edges x 16 col-lanes ----------------

__global__ __launch_bounds__(256) void k_agg1(
        const int* __restrict__ rowstart, const int* __restrict__ sorted_src,
        const float* __restrict__ el1, const float* __restrict__ er1,
        const __half* __restrict__ feat1h, const float* __restrict__ b1,
        float* __restrict__ h) {
    int tid = threadIdx.x;
    int d = blockIdx.x * 4 + (tid >> 6);   // 50000 % 4 == 0
    int lane = tid & 63;
    int eg = lane >> 4;                    // edge group 0..3
    int cl = lane & 15;                    // col-lane: cols 8*cl..8*cl+7
    int head = cl >> 2;
    float er = er1[d * 4 + head];
    int start = rowstart[d], end = rowstart[d + 1];
    float acc[8];
    #pragma unroll
    for (int k = 0; k < 8; k++) acc[k] = 0.f;
    float wsum = 0.f;

    for (int i = start; i < end; i += 8) {
        int e0 = i + eg, e1 = i + 4 + eg;
        bool ok0 = e0 < end, ok1 = e1 < end;
        int e0c = ok0 ? e0 : end - 1;
        int e1c = ok1 ? e1 : end - 1;
        int s0 = sorted_src[e0c];
        int s1 = sorted_src[e1c];
        float el0v = el1[s0 * 4 + head];
        float el1v = el1[s1 * 4 + head];
        float4 r0 = *(const float4*)(feat1h + (size_t)s0 * HD + cl * 8);
        float4 r1 = *(const float4*)(feat1h + (size_t)s1 * HD + cl * 8);
        float w0 = ok0 ? lexp(el0v + er) : 0.f;
        float w1 = ok1 ? lexp(el1v + er) : 0.f;
        const __half2* p0 = (const __half2*)&r0;
        const __half2* p1 = (const __half2*)&r1;
        #pragma unroll
        for (int q = 0; q < 4; q++) {
            float2 f0 = __half22float2(p0[q]);
            float2 f1 = __half22float2(p1[q]);
            acc[2 * q]     += w0 * f0.x + w1 * f1.x;
            acc[2 * q + 1] += w0 * f0.y + w1 * f1.y;
        }
        wsum += w0 + w1;
    }
    #pragma unroll
    for (int k = 0; k < 8; k++) {
        acc[k] += __shfl_xor(acc[k], 16);
        acc[k] += __shfl_xor(acc[k], 32);
    }
    wsum += __shfl_xor(wsum, 16);
    wsum += __shfl_xor(wsum, 32);
    if (eg == 0) {
        float inv = 1.f / fmaxf(wsum, 1e-9f);
        float v[8];
        #pragma unroll
        for (int k = 0; k < 8; k++) v[k] = elu1(acc[k] * inv + b1[cl * 8 + k]);
        float4* hp = (float4*)(h + (size_t)d * HD + cl * 8);
        hp[0] = make_float4(v[0], v[1], v[2], v[3]);
        hp[1] = make_float4(v[4], v[5], v[6], v[7]);
    }
}

// ---------------- Layer 2 GEMM: feat2 = h @ W2, fused el2/er2 ----------------

__global__ __launch_bounds__(256) void k_gemm2(
        const float* __restrict__ h, const float* __restrict__ W2,
        const float* __restrict__ al2, const float* __restrict__ ar2,
        float* __restrict__ feat2, float* __restrict__ el2, float* __restrict__ er2) {
    __shared__ float hs[16 * 132];
    __shared__ float w2t[16 * 132];
    int tid = threadIdx.x;
    int nb = blockIdx.x * 16;  // 50000 % 16 == 0
    for (int idx = tid; idx < 512; idx += 256) {
        int row = idx >> 5, kk = idx & 31;
        ((float4*)(hs + row * 132))[kk] = ((const float4*)h)[(size_t)(nb + row) * 32 + kk];
    }
    for (int idx = tid; idx < 2048; idx += 256) {
        int k = idx >> 4, c = idx & 15;
        w2t[c * 132 + k] = W2[idx];
    }
    __syncthreads();
    int nl = tid >> 4, col = tid & 15;
    const float4* hv = (const float4*)(hs + nl * 132);
    const float4* wv = (const float4*)(w2t + col * 132);
    float acc = 0.f;
    #pragma unroll
    for (int kk = 0; kk < 32; kk++) {
        float4 a = hv[kk], w = wv[kk];
        acc += a.x * w.x + a.y * w.y + a.z * w.z + a.w * w.w;
    }
    int node = nb + nl;
    feat2[node * 16 + col] = acc;
    float pl = acc * al2[col], pr = acc * ar2[col];
    #pragma unroll
    for (int m = 8; m >= 1; m >>= 1) {
        pl += __shfl_xor(pl, m);
        pr += __shfl_xor(pr, m);
    }
    if (col == 0) { el2[node] = pl; er2[node] = pr; }
}

// ---------------- Layer 2 aggregation: wave per dst, 16 edges x 4 col-lanes ----------------

__global__ __launch_bounds__(256) void k_agg2(
        const int* __restrict__ rowstart, const int* __restrict__ sorted_src,
        const float* __restrict__ el2, const float* __restrict__ er2,
        const float* __restrict__ feat2, const float* __restrict__ b2,
        float* __restrict__ out) {
    int tid = threadIdx.x;
    int d = blockIdx.x * 4 + (tid >> 6);   // 50000 % 4 == 0
    int lane = tid & 63;
    int eg = lane >> 2;                    // edge group 0..15
    int cq = lane & 3;                     // cols 4*cq..4*cq+3
    float er = er2[d];
    int start = rowstart[d], end = rowstart[d + 1];
    float4 acc = make_float4(0.f, 0.f, 0.f, 0.f);
    float wsum = 0.f;
    for (int i = start; i < end; i += 16) {
        int e = i + eg;
        bool ok = e < end;
        int ec = ok ? e : end - 1;
        int s = sorted_src[ec];
        float elv = el2[s];
        float4 f = ((const float4*)feat2)[(size_t)s * 4 + cq];
        float ev = elv + er;
        float wr = __expf(ev > 0.f ? ev : NEG * ev);
        float w = ok ? wr : 0.f;
        acc.x += w * f.x; acc.y += w * f.y; acc.z += w * f.z; acc.w += w * f.w;
        wsum += w;
    }
    #pragma unroll
    for (int m = 4; m <= 32; m <<= 1) {
        acc.x += __shfl_xor(acc.x, m);
        acc.y += __shfl_xor(acc.y, m);
        acc.z += __shfl_xor(acc.z, m);
        acc.w += __shfl_xor(acc.w, m);
        wsum  += __shfl_xor(wsum, m);
    }
    if (lane < 4) {
        float inv = 1.f / fmaxf(wsum, 1e-9f);
        float4 bv = ((const float4*)b2)[cq];
        float4 o = make_float4(acc.x * inv + bv.x, acc.y * inv + bv.y,
                               acc.z * inv + bv.z, acc.w * inv + bv.w);
        ((float4*)out)[(size_t)d * 4 + cq] = o;
    }
}

// ---------------- launch ----------------

extern "C" void kernel_launch(void* const* d_in, const int* in_sizes, int n_in,
                              void* d_out, int out_size, void* d_ws, size_t ws_size,
                              hipStream_t stream) {
    const float* x   = (const float*)d_in[0];
    const int*   src = (const int*)d_in[1];
    const int*   dst = (const int*)d_in[2];
    const float* W1  = (const float*)d_in[3];
    const float* b1  = (const float*)d_in[4];
    const float* al1 = (const float*)d_in[5];
    const float* ar1 = (const float*)d_in[6];
    const float* W2  = (const float*)d_in[7];
    const float* b2  = (const float*)d_in[8];
    const float* al2 = (const float*)d_in[9];
    const float* ar2 = (const float*)d_in[10];
    float* out = (float*)d_out;

    char* ws = (char*)d_ws;
    size_t off = 0;
    auto alloc = [&](size_t bytes) -> char* {
        char* p = ws + off;
        off += (bytes + 255) & ~(size_t)255;
        return p;
    };
    __half* feat1h    = (__half*)alloc((size_t)N_NODES * HD * 2);
    float* h          = (float*)alloc((size_t)N_NODES * HD * 4);
    float* el1        = (float*)alloc((size_t)N_NODES * 4 * 4);
    float* er1        = (float*)alloc((size_t)N_NODES * 4 * 4);
    float* feat2      = (float*)alloc((size_t)N_NODES * C2 * 4);
    float* el2        = (float*)alloc((size_t)N_NODES * 4);
    float* er2        = (float*)alloc((size_t)N_NODES * 4);
    int*   ghist      = (int*)alloc((size_t)NBUCK * NBLK * 4);
    int*   bucket_tot = (int*)alloc((size_t)NBUCK * 4);
    int*   bucket_base= (int*)alloc((size_t)(NBUCK + 1) * 4);
    int*   rowstart   = (int*)alloc((size_t)(N_NODES + 1) * 4);
    int*   ebuf       = (int*)alloc((size_t)N_EDGES * 4);
    int*   sorted_src = (int*)alloc((size_t)N_EDGES * 4);

    k_bhist<<<NBLK, 256, 0, stream>>>(dst, ghist);
    k_bscan1<<<NBUCK, 256, 0, stream>>>(ghist, bucket_tot);
    k_bscan2<<<1, 512, 0, stream>>>(bucket_tot, bucket_base, rowstart);
    k_bscatter<<<NBLK, 256, 0, stream>>>(src, dst, ghist, bucket_base, ebuf);
    k_bsort<<<NBUCK, 256, 0, stream>>>(ebuf, bucket_base, sorted_src, rowstart);
    k_gemm1<<<(N_NODES + 63) / 64, 256, 0, stream>>>(x, W1, al1, ar1, feat1h, el1, er1);
    k_agg1<<<N_NODES / 4, 256, 0, stream>>>(rowstart, sorted_src, el1, er1, feat1h, b1, h);
    k_gemm2<<<N_NODES / 16, 256, 0, stream>>>(h, W2, al2, ar2, feat2, el2, er2);
    k_agg2<<<N_NODES / 4, 256, 0, stream>>>(rowstart, sorted_src, el2, er2, feat2, b2, out);
}

// Round 9
// 245.861 us; speedup vs baseline: 1.8682x; 1.1154x over previous
//
#include <hip/hip_runtime.h>
#include <hip/hip_fp16.h>

#define N_NODES 50000
#define N_EDGES 1600000
#define FIN 256
#define HD 128          // HEADS*HIDDEN
#define NHEADS 4
#define C2 16           // NUM_CLASSES
#define NEG 0.2f

// bucketed counting-sort CSR build
#define EBLK 4096
#define NBLK 391        // ceil(N_EDGES/EBLK)
#define NBUCK 391       // ceil(N_NODES/128)
#define BSH 7
#define BMASK 127
#define MAXB 5120       // bucket capacity: mean 4096, sigma ~64 -> +16 sigma

typedef _Float16 v8h __attribute__((ext_vector_type(8)));
typedef float v4f __attribute__((ext_vector_type(4)));
union F4H8 { float4 f; v8h h; };

__device__ __forceinline__ float elu1(float x) { return x > 0.f ? x : __expf(x) - 1.f; }
__device__ __forceinline__ float lexp(float e) { return __expf(e > 0.f ? e : NEG * e); }

// ---------------- CSR build: bucketed counting sort ----------------

__global__ __launch_bounds__(256) void k_bhist(const int* __restrict__ dst,
                                               int* __restrict__ ghist) {
    __shared__ int lh[NBUCK];
    int tid = threadIdx.x, b = blockIdx.x;
    for (int t = tid; t < NBUCK; t += 256) lh[t] = 0;
    __syncthreads();
    int base = b * EBLK;
    int nq = (min(EBLK, N_EDGES - base)) >> 2;
    const int4* d4 = (const int4*)(dst + base);
    for (int q = tid; q < nq; q += 256) {
        int4 d = d4[q];
        atomicAdd(&lh[d.x >> BSH], 1);
        atomicAdd(&lh[d.y >> BSH], 1);
        atomicAdd(&lh[d.z >> BSH], 1);
        atomicAdd(&lh[d.w >> BSH], 1);
    }
    __syncthreads();
    for (int t = tid; t < NBUCK; t += 256) ghist[t * NBLK + b] = lh[t];
}

__global__ __launch_bounds__(256) void k_bscan1(int* __restrict__ ghist,
                                                int* __restrict__ bucket_tot) {
    __shared__ int s[256];
    int B = blockIdx.x, t = threadIdx.x;
    int* row = ghist + (size_t)B * NBLK;
    int i0 = 2 * t, i1 = 2 * t + 1;
    int a0 = (i0 < NBLK) ? row[i0] : 0;
    int a1 = (i1 < NBLK) ? row[i1] : 0;
    int pair = a0 + a1;
    s[t] = pair;
    __syncthreads();
    for (int off = 1; off < 256; off <<= 1) {
        int u = (t >= off) ? s[t - off] : 0;
        __syncthreads();
        s[t] += u;
        __syncthreads();
    }
    int excl = s[t] - pair;
    if (i0 < NBLK) row[i0] = excl;
    if (i1 < NBLK) row[i1] = excl + a0;
    if (t == 255) bucket_tot[B] = s[255];
}

__global__ __launch_bounds__(512) void k_bscan2(const int* __restrict__ bucket_tot,
                                                int* __restrict__ bucket_base,
                                                int* __restrict__ rowstart) {
    __shared__ int s[512];
    int t = threadIdx.x;
    int v = (t < NBUCK) ? bucket_tot[t] : 0;
    s[t] = v;
    __syncthreads();
    for (int off = 1; off < 512; off <<= 1) {
        int u = (t >= off) ? s[t - off] : 0;
        __syncthreads();
        s[t] += u;
        __syncthreads();
    }
    if (t < NBUCK) bucket_base[t] = s[t] - v;
    if (t == 0) { bucket_base[NBUCK] = N_EDGES; rowstart[N_NODES] = N_EDGES; }
}

__global__ __launch_bounds__(256) void k_bscatter(
        const int* __restrict__ src, const int* __restrict__ dst,
        const int* __restrict__ ghist, const int* __restrict__ bucket_base,
        int* __restrict__ ebuf) {
    __shared__ int lcur[NBUCK];
    int tid = threadIdx.x, b = blockIdx.x;
    for (int t = tid; t < NBUCK; t += 256)
        lcur[t] = bucket_base[t] + ghist[t * NBLK + b];
    __syncthreads();
    int base = b * EBLK;
    int nq = (min(EBLK, N_EDGES - base)) >> 2;
    const int4* s4 = (const int4*)(src + base);
    const int4* d4 = (const int4*)(dst + base);
    for (int q = tid; q < nq; q += 256) {
        int4 s = s4[q];
        int4 d = d4[q];
        int p;
        p = atomicAdd(&lcur[d.x >> BSH], 1); ebuf[p] = (s.x << BSH) | (d.x & BMASK);
        p = atomicAdd(&lcur[d.y >> BSH], 1); ebuf[p] = (s.y << BSH) | (d.y & BMASK);
        p = atomicAdd(&lcur[d.z >> BSH], 1); ebuf[p] = (s.z << BSH) | (d.z & BMASK);
        p = atomicAdd(&lcur[d.w >> BSH], 1); ebuf[p] = (s.w << BSH) | (d.w & BMASK);
    }
}

__global__ __launch_bounds__(256) void k_bsort(
        const int* __restrict__ ebuf, const int* __restrict__ bucket_base,
        int* __restrict__ sorted_src, int* __restrict__ rowstart) {
    __shared__ int ein[MAXB];
    __shared__ int eout[MAXB];
    __shared__ int hist[128];
    __shared__ int sc[128];
    __shared__ int cursor[128];
    int tid = threadIdx.x, B = blockIdx.x;
    int base = bucket_base[B];
    int n = bucket_base[B + 1] - base;
    if (tid < 128) hist[tid] = 0;
    __syncthreads();
    for (int i = tid; i < n; i += 256) {
        int v = ebuf[base + i];
        ein[i] = v;
        atomicAdd(&hist[v & BMASK], 1);
    }
    __syncthreads();
    if (tid < 128) sc[tid] = hist[tid];
    __syncthreads();
    for (int off = 1; off < 128; off <<= 1) {
        int u = 0;
        if (tid < 128 && tid >= off) u = sc[tid - off];
        __syncthreads();
        if (tid < 128) sc[tid] += u;
        __syncthreads();
    }
    if (tid < 128) {
        int ex = sc[tid] - hist[tid];
        cursor[tid] = ex;
        int node = B * 128 + tid;
        if (node < N_NODES) rowstart[node] = base + ex;
    }
    __syncthreads();
    for (int i = tid; i < n; i += 256) {
        int v = ein[i];
        int p = atomicAdd(&cursor[v & BMASK], 1);
        eout[p] = v >> BSH;
    }
    __syncthreads();
    for (int i = tid; i < n; i += 256) sorted_src[base + i] = eout[i];
}

// ---------------- W1 -> fp16 transposed [col][k] ----------------

__global__ __launch_bounds__(256) void k_w1half(const float* __restrict__ W1,
                                                _Float16* __restrict__ W1T) {
    int idx = blockIdx.x * 256 + threadIdx.x;   // 32768 total
    int k = idx >> 7, c = idx & 127;
    W1T[c * 256 + k] = (_Float16)W1[idx];
}

// ---------------- Layer 1 GEMM via MFMA fp16: feat1 = x @ W1, fused el1/er1 ----
// BM=64 x BN=128 x BK=32, 4 waves, wave tile 32x64 (2x4 mfma_f32_16x16x32_f16).
// XOR-swizzled 16B-chunk LDS layout: chunk(node,ch) at [node*4 + (ch^(node&3))]
// -> all ds_read/ds_write b128 conflict-free. 1-deep register prefetch.

__global__ __launch_bounds__(256) void k_gemm1(
        const float* __restrict__ x, const _Float16* __restrict__ W1T,
        const float* __restrict__ al1, const float* __restrict__ ar1,
        __half* __restrict__ feat1h, float* __restrict__ el1, float* __restrict__ er1) {
    __shared__ v8h As[64 * 4];    // 64 nodes x 32k fp16, 4 KB
    __shared__ v8h Bs[128 * 4];   // 128 cols x 32k fp16, 8 KB
    int tid = threadIdx.x;
    int nb = blockIdx.x * 64;
    int wid = tid >> 6, lane = tid & 63;
    int wm = wid & 1, wn = wid >> 1;      // wave tile: rows wm*32.., cols wn*64..
    int q = lane >> 4, lm = lane & 15;

    // staging roles
    int anode = tid >> 2, ach = tid & 3;  // A: node x k-chunk(8)
    int gnode = nb + anode; if (gnode >= N_NODES) gnode = N_NODES - 1;
    const float4* xrow = (const float4*)(x + (size_t)gnode * FIN);
    int bc = tid >> 2, bch = tid & 3;     // B: this thread stages cols bc and bc+64

    v4f acc[2][4];
    #pragma unroll
    for (int mt = 0; mt < 2; mt++)
        #pragma unroll
        for (int nt = 0; nt < 4; nt++) acc[mt][nt] = (v4f)(0.f);

    // prefetch step 0
    float4 xa0 = xrow[ach * 2];
    float4 xa1 = xrow[ach * 2 + 1];
    F4H8 wb0, wb1;
    wb0.f = *(const float4*)(W1T + bc * 256 + bch * 8);
    wb1.f = *(const float4*)(W1T + (bc + 64) * 256 + bch * 8);

    for (int step = 0; step < 8; step++) {
        __syncthreads();   // previous compute done before LDS overwrite
        {
            v8h av;
            av[0] = (_Float16)xa0.x; av[1] = (_Float16)xa0.y;
            av[2] = (_Float16)xa0.z; av[3] = (_Float16)xa0.w;
            av[4] = (_Float16)xa1.x; av[5] = (_Float16)xa1.y;
            av[6] = (_Float16)xa1.z; av[7] = (_Float16)xa1.w;
            As[anode * 4 + (ach ^ (anode & 3))] = av;
            Bs[bc * 4 + (bch ^ (bc & 3))] = wb0.h;
            Bs[(bc + 64) * 4 + (bch ^ (bc & 3))] = wb1.h;
        }
        __syncthreads();
        if (step < 7) {
            int k0 = (step + 1) * 32;
            xa0 = xrow[(k0 >> 2) + ach * 2];
            xa1 = xrow[(k0 >> 2) + ach * 2 + 1];
            wb0.f = *(const float4*)(W1T + bc * 256 + k0 + bch * 8);
            wb1.f = *(const float4*)(W1T + (bc + 64) * 256 + k0 + bch * 8);
        }
        v8h af[2], bf[4];
        #pragma unroll
        for (int mt = 0; mt < 2; mt++) {
            int nl = wm * 32 + mt * 16 + lm;
            af[mt] = As[nl * 4 + (q ^ (nl & 3))];
        }
        #pragma unroll
        for (int nt = 0; nt < 4; nt++) {
            int cl = wn * 64 + nt * 16 + lm;
            bf[nt] = Bs[cl * 4 + (q ^ (cl & 3))];
        }
        #pragma unroll
        for (int mt = 0; mt < 2; mt++)
            #pragma unroll
            for (int nt = 0; nt < 4; nt++)
                acc[mt][nt] = __builtin_amdgcn_mfma_f32_16x16x32_f16(
                    af[mt], bf[nt], acc[mt][nt], 0, 0, 0);
    }

    // epilogue: feat1h stores + fused el/er.
    // D layout: row = q*4 + r, col = lm (per 16x16 frag).
    float alv[4], arv[4];
    #pragma unroll
    for (int nt = 0; nt < 4; nt++) {
        alv[nt] = al1[wn * 64 + nt * 16 + lm];
        arv[nt] = ar1[wn * 64 + nt * 16 + lm];
    }
    int h0 = 2 * wn, h1 = 2 * wn + 1;
    #pragma unroll
    for (int mt = 0; mt < 2; mt++) {
        #pragma unroll
        for (int r = 0; r < 4; r++) {
            int node = nb + wm * 32 + mt * 16 + q * 4 + r;
            bool ok = node < N_NODES;
            float v0 = acc[mt][0][r], v1 = acc[mt][1][r];
            float v2 = acc[mt][2][r], v3 = acc[mt][3][r];
            if (ok) {
                __half* fp = feat1h + (size_t)node * HD + wn * 64 + lm;
                fp[0]  = __float2half(v0);
                fp[16] = __float2half(v1);
                fp[32] = __float2half(v2);
                fp[48] = __float2half(v3);
            }
            float pl0 = v0 * alv[0] + v1 * alv[1];
            float pr0 = v0 * arv[0] + v1 * arv[1];
            float pl1 = v2 * alv[2] + v3 * alv[3];
            float pr1 = v2 * arv[2] + v3 * arv[3];
            #pragma unroll
            for (int m = 1; m <= 8; m <<= 1) {
                pl0 += __shfl_xor(pl0, m); pr0 += __shfl_xor(pr0, m);
                pl1 += __shfl_xor(pl1, m); pr1 += __shfl_xor(pr1, m);
            }
            if (ok && lm == 0) {
                el1[node * 4 + h0] = pl0; er1[node * 4 + h0] = pr0;
                el1[node * 4 + h1] = pl1; er1[node * 4 + h1] = pr1;
            }
        }
    }
}

// ---------------- Layer 1 aggregation: wave per dst, 4 edges x 16 col-lanes ----------------

__global__ __launch_bounds__(256) void k_agg1(
        const int* __restrict__ rowstart, const int* __restrict__ sorted_src,
        const float* __restrict__ el1, const float* __restrict__ er1,
        const __half* __restrict__ feat1h, const float* __restrict__ b1,
        float* __restrict__ h) {
    int tid = threadIdx.x;
    int d = blockIdx.x * 4 + (tid >> 6);   // 50000 % 4 == 0
    int lane = tid & 63;
    int eg = lane >> 4;                    // edge group 0..3
    int cl = lane & 15;                    // col-lane: cols 8*cl..8*cl+7
    int head = cl >> 2;
    float er = er1[d * 4 + head];
    int start = rowstart[d], end = rowstart[d + 1];
    float acc[8];
    #pragma unroll
    for (int k = 0; k < 8; k++) acc[k] = 0.f;
    float wsum = 0.f;

    for (int i = start; i < end; i += 8) {
        int e0 = i + eg, e1 = i + 4 + eg;
        bool ok0 = e0 < end, ok1 = e1 < end;
        int e0c = ok0 ? e0 : end - 1;
        int e1c = ok1 ? e1 : end - 1;
        int s0 = sorted_src[e0c];
        int s1 = sorted_src[e1c];
        float el0v = el1[s0 * 4 + head];
        float el1v = el1[s1 * 4 + head];
        float4 r0 = *(const float4*)(feat1h + (size_t)s0 * HD + cl * 8);
        float4 r1 = *(const float4*)(feat1h + (size_t)s1 * HD + cl * 8);
        float w0 = ok0 ? lexp(el0v + er) : 0.f;
        float w1 = ok1 ? lexp(el1v + er) : 0.f;
        const __half2* p0 = (const __half2*)&r0;
        const __half2* p1 = (const __half2*)&r1;
        #pragma unroll
        for (int q = 0; q < 4; q++) {
            float2 f0 = __half22float2(p0[q]);
            float2 f1 = __half22float2(p1[q]);
            acc[2 * q]     += w0 * f0.x + w1 * f1.x;
            acc[2 * q + 1] += w0 * f0.y + w1 * f1.y;
        }
        wsum += w0 + w1;
    }
    #pragma unroll
    for (int k = 0; k < 8; k++) {
        acc[k] += __shfl_xor(acc[k], 16);
        acc[k] += __shfl_xor(acc[k], 32);
    }
    wsum += __shfl_xor(wsum, 16);
    wsum += __shfl_xor(wsum, 32);
    if (eg == 0) {
        float inv = 1.f / fmaxf(wsum, 1e-9f);
        float v[8];
        #pragma unroll
        for (int k = 0; k < 8; k++) v[k] = elu1(acc[k] * inv + b1[cl * 8 + k]);
        float4* hp = (float4*)(h + (size_t)d * HD + cl * 8);
        hp[0] = make_float4(v[0], v[1], v[2], v[3]);
        hp[1] = make_float4(v[4], v[5], v[6], v[7]);
    }
}

// ---------------- Layer 2 GEMM: feat2 = h @ W2, fused el2/er2 ----------------

__global__ __launch_bounds__(256) void k_gemm2(
        const float* __restrict__ h, const float* __restrict__ W2,
        const float* __restrict__ al2, const float* __restrict__ ar2,
        float* __restrict__ feat2, float* __restrict__ el2, float* __restrict__ er2) {
    __shared__ float hs[16 * 132];
    __shared__ float w2t[16 * 132];
    int tid = threadIdx.x;
    int nb = blockIdx.x * 16;  // 50000 % 16 == 0
    for (int idx = tid; idx < 512; idx += 256) {
        int row = idx >> 5, kk = idx & 31;
        ((float4*)(hs + row * 132))[kk] = ((const float4*)h)[(size_t)(nb + row) * 32 + kk];
    }
    for (int idx = tid; idx < 2048; idx += 256) {
        int k = idx >> 4, c = idx & 15;
        w2t[c * 132 + k] = W2[idx];
    }
    __syncthreads();
    int nl = tid >> 4, col = tid & 15;
    const float4* hv = (const float4*)(hs + nl * 132);
    const float4* wv = (const float4*)(w2t + col * 132);
    float acc = 0.f;
    #pragma unroll
    for (int kk = 0; kk < 32; kk++) {
        float4 a = hv[kk], w = wv[kk];
        acc += a.x * w.x + a.y * w.y + a.z * w.z + a.w * w.w;
    }
    int node = nb + nl;
    feat2[node * 16 + col] = acc;
    float pl = acc * al2[col], pr = acc * ar2[col];
    #pragma unroll
    for (int m = 8; m >= 1; m >>= 1) {
        pl += __shfl_xor(pl, m);
        pr += __shfl_xor(pr, m);
    }
    if (col == 0) { el2[node] = pl; er2[node] = pr; }
}

// ---------------- Layer 2 aggregation: wave per dst, 16 edges x 4 col-lanes ----------------

__global__ __launch_bounds__(256) void k_agg2(
        const int* __restrict__ rowstart, const int* __restrict__ sorted_src,
        const float* __restrict__ el2, const float* __restrict__ er2,
        const float* __restrict__ feat2, const float* __restrict__ b2,
        float* __restrict__ out) {
    int tid = threadIdx.x;
    int d = blockIdx.x * 4 + (tid >> 6);   // 50000 % 4 == 0
    int lane = tid & 63;
    int eg = lane >> 2;                    // edge group 0..15
    int cq = lane & 3;                     // cols 4*cq..4*cq+3
    float er = er2[d];
    int start = rowstart[d], end = rowstart[d + 1];
    float4 acc = make_float4(0.f, 0.f, 0.f, 0.f);
    float wsum = 0.f;
    for (int i = start; i < end; i += 16) {
        int e = i + eg;
        bool ok = e < end;
        int ec = ok ? e : end - 1;
        int s = sorted_src[ec];
        float elv = el2[s];
        float4 f = ((const float4*)feat2)[(size_t)s * 4 + cq];
        float ev = elv + er;
        float wr = __expf(ev > 0.f ? ev : NEG * ev);
        float w = ok ? wr : 0.f;
        acc.x += w * f.x; acc.y += w * f.y; acc.z += w * f.z; acc.w += w * f.w;
        wsum += w;
    }
    #pragma unroll
    for (int m = 4; m <= 32; m <<= 1) {
        acc.x += __shfl_xor(acc.x, m);
        acc.y += __shfl_xor(acc.y, m);
        acc.z += __shfl_xor(acc.z, m);
        acc.w += __shfl_xor(acc.w, m);
        wsum  += __shfl_xor(wsum, m);
    }
    if (lane < 4) {
        float inv = 1.f / fmaxf(wsum, 1e-9f);
        float4 bv = ((const float4*)b2)[cq];
        float4 o = make_float4(acc.x * inv + bv.x, acc.y * inv + bv.y,
                               acc.z * inv + bv.z, acc.w * inv + bv.w);
        ((float4*)out)[(size_t)d * 4 + cq] = o;
    }
}

// ---------------- launch ----------------

extern "C" void kernel_launch(void* const* d_in, const int* in_sizes, int n_in,
                              void* d_out, int out_size, void* d_ws, size_t ws_size,
                              hipStream_t stream) {
    const float* x   = (const float*)d_in[0];
    const int*   src = (const int*)d_in[1];
    const int*   dst = (const int*)d_in[2];
    const float* W1  = (const float*)d_in[3];
    const float* b1  = (const float*)d_in[4];
    const float* al1 = (const float*)d_in[5];
    const float* ar1 = (const float*)d_in[6];
    const float* W2  = (const float*)d_in[7];
    const float* b2  = (const float*)d_in[8];
    const float* al2 = (const float*)d_in[9];
    const float* ar2 = (const float*)d_in[10];
    float* out = (float*)d_out;

    char* ws = (char*)d_ws;
    size_t off = 0;
    auto alloc = [&](size_t bytes) -> char* {
        char* p = ws + off;
        off += (bytes + 255) & ~(size_t)255;
        return p;
    };
    __half* feat1h     = (__half*)alloc((size_t)N_NODES * HD * 2);
    _Float16* W1T      = (_Float16*)alloc((size_t)FIN * HD * 2);
    float* h           = (float*)alloc((size_t)N_NODES * HD * 4);
    float* el1         = (float*)alloc((size_t)N_NODES * 4 * 4);
    float* er1         = (float*)alloc((size_t)N_NODES * 4 * 4);
    float* feat2       = (float*)alloc((size_t)N_NODES * C2 * 4);
    float* el2         = (float*)alloc((size_t)N_NODES * 4);
    float* er2         = (float*)alloc((size_t)N_NODES * 4);
    int*   ghist       = (int*)alloc((size_t)NBUCK * NBLK * 4);
    int*   bucket_tot  = (int*)alloc((size_t)NBUCK * 4);
    int*   bucket_base = (int*)alloc((size_t)(NBUCK + 1) * 4);
    int*   rowstart    = (int*)alloc((size_t)(N_NODES + 1) * 4);
    int*   ebuf        = (int*)alloc((size_t)N_EDGES * 4);
    int*   sorted_src  = (int*)alloc((size_t)N_EDGES * 4);

    k_bhist<<<NBLK, 256, 0, stream>>>(dst, ghist);
    k_bscan1<<<NBUCK, 256, 0, stream>>>(ghist, bucket_tot);
    k_bscan2<<<1, 512, 0, stream>>>(bucket_tot, bucket_base, rowstart);
    k_bscatter<<<NBLK, 256, 0, stream>>>(src, dst, ghist, bucket_base, ebuf);
    k_bsort<<<NBUCK, 256, 0, stream>>>(ebuf, bucket_base, sorted_src, rowstart);
    k_w1half<<<128, 256, 0, stream>>>(W1, W1T);
    k_gemm1<<<(N_NODES + 63) / 64, 256, 0, stream>>>(x, W1T, al1, ar1, feat1h, el1, er1);
    k_agg1<<<N_NODES / 4, 256, 0, stream>>>(rowstart, sorted_src, el1, er1, feat1h, b1, h);
    k_gemm2<<<N_NODES / 16, 256, 0, stream>>>(h, W2, al2, ar2, feat2, el2, er2);
    k_agg2<<<N_NODES / 4, 256, 0, stream>>>(rowstart, sorted_src, el2, er2, feat2, b2, out);
}

// Round 10
// 244.211 us; speedup vs baseline: 1.8809x; 1.0068x over previous
//
#include <hip/hip_runtime.h>
#include <hip/hip_fp16.h>

#define N_NODES 50000
#define N_EDGES 1600000
#define FIN 256
#define HD 128          // HEADS*HIDDEN
#define NHEADS 4
#define C2 16           // NUM_CLASSES
#define NEG 0.2f

// bucketed counting-sort CSR build
#define EBLK 4096
#define NBLK 391        // ceil(N_EDGES/EBLK)
#define NBUCK 391       // ceil(N_NODES/128)
#define BSH 7
#define BMASK 127
#define MAXB 5120       // bucket capacity: mean 4096, sigma ~64 -> +16 sigma

typedef _Float16 v8h __attribute__((ext_vector_type(8)));
typedef float v4f __attribute__((ext_vector_type(4)));
union F4H8 { float4 f; v8h h; };

__device__ __forceinline__ float elu1(float x) { return x > 0.f ? x : __expf(x) - 1.f; }
__device__ __forceinline__ float lexp(float e) { return __expf(e > 0.f ? e : NEG * e); }

// ---------------- CSR build: bucketed counting sort ----------------

__global__ __launch_bounds__(256) void k_bhist(const int* __restrict__ dst,
                                               int* __restrict__ ghist) {
    __shared__ int lh[NBUCK];
    int tid = threadIdx.x, b = blockIdx.x;
    for (int t = tid; t < NBUCK; t += 256) lh[t] = 0;
    __syncthreads();
    int base = b * EBLK;
    int nq = (min(EBLK, N_EDGES - base)) >> 2;
    const int4* d4 = (const int4*)(dst + base);
    for (int q = tid; q < nq; q += 256) {
        int4 d = d4[q];
        atomicAdd(&lh[d.x >> BSH], 1);
        atomicAdd(&lh[d.y >> BSH], 1);
        atomicAdd(&lh[d.z >> BSH], 1);
        atomicAdd(&lh[d.w >> BSH], 1);
    }
    __syncthreads();
    for (int t = tid; t < NBUCK; t += 256) ghist[t * NBLK + b] = lh[t];
}

__global__ __launch_bounds__(256) void k_bscan1(int* __restrict__ ghist,
                                                int* __restrict__ bucket_tot) {
    __shared__ int s[256];
    int B = blockIdx.x, t = threadIdx.x;
    int* row = ghist + (size_t)B * NBLK;
    int i0 = 2 * t, i1 = 2 * t + 1;
    int a0 = (i0 < NBLK) ? row[i0] : 0;
    int a1 = (i1 < NBLK) ? row[i1] : 0;
    int pair = a0 + a1;
    s[t] = pair;
    __syncthreads();
    for (int off = 1; off < 256; off <<= 1) {
        int u = (t >= off) ? s[t - off] : 0;
        __syncthreads();
        s[t] += u;
        __syncthreads();
    }
    int excl = s[t] - pair;
    if (i0 < NBLK) row[i0] = excl;
    if (i1 < NBLK) row[i1] = excl + a0;
    if (t == 255) bucket_tot[B] = s[255];
}

__global__ __launch_bounds__(512) void k_bscan2(const int* __restrict__ bucket_tot,
                                                int* __restrict__ bucket_base,
                                                int* __restrict__ rowstart) {
    __shared__ int s[512];
    int t = threadIdx.x;
    int v = (t < NBUCK) ? bucket_tot[t] : 0;
    s[t] = v;
    __syncthreads();
    for (int off = 1; off < 512; off <<= 1) {
        int u = (t >= off) ? s[t - off] : 0;
        __syncthreads();
        s[t] += u;
        __syncthreads();
    }
    if (t < NBUCK) bucket_base[t] = s[t] - v;
    if (t == 0) { bucket_base[NBUCK] = N_EDGES; rowstart[N_NODES] = N_EDGES; }
}

__global__ __launch_bounds__(256) void k_bscatter(
        const int* __restrict__ src, const int* __restrict__ dst,
        const int* __restrict__ ghist, const int* __restrict__ bucket_base,
        int* __restrict__ ebuf) {
    __shared__ int lcur[NBUCK];
    int tid = threadIdx.x, b = blockIdx.x;
    for (int t = tid; t < NBUCK; t += 256)
        lcur[t] = bucket_base[t] + ghist[t * NBLK + b];
    __syncthreads();
    int base = b * EBLK;
    int nq = (min(EBLK, N_EDGES - base)) >> 2;
    const int4* s4 = (const int4*)(src + base);
    const int4* d4 = (const int4*)(dst + base);
    for (int q = tid; q < nq; q += 256) {
        int4 s = s4[q];
        int4 d = d4[q];
        int p;
        p = atomicAdd(&lcur[d.x >> BSH], 1); ebuf[p] = (s.x << BSH) | (d.x & BMASK);
        p = atomicAdd(&lcur[d.y >> BSH], 1); ebuf[p] = (s.y << BSH) | (d.y & BMASK);
        p = atomicAdd(&lcur[d.z >> BSH], 1); ebuf[p] = (s.z << BSH) | (d.z & BMASK);
        p = atomicAdd(&lcur[d.w >> BSH], 1); ebuf[p] = (s.w << BSH) | (d.w & BMASK);
    }
}

__global__ __launch_bounds__(256) void k_bsort(
        const int* __restrict__ ebuf, const int* __restrict__ bucket_base,
        int* __restrict__ sorted_src, int* __restrict__ rowstart) {
    __shared__ int ein[MAXB];
    __shared__ int eout[MAXB];
    __shared__ int hist[128];
    __shared__ int sc[128];
    __shared__ int cursor[128];
    int tid = threadIdx.x, B = blockIdx.x;
    int base = bucket_base[B];
    int n = bucket_base[B + 1] - base;
    if (tid < 128) hist[tid] = 0;
    __syncthreads();
    for (int i = tid; i < n; i += 256) {
        int v = ebuf[base + i];
        ein[i] = v;
        atomicAdd(&hist[v & BMASK], 1);
    }
    __syncthreads();
    if (tid < 128) sc[tid] = hist[tid];
    __syncthreads();
    for (int off = 1; off < 128; off <<= 1) {
        int u = 0;
        if (tid < 128 && tid >= off) u = sc[tid - off];
        __syncthreads();
        if (tid < 128) sc[tid] += u;
        __syncthreads();
    }
    if (tid < 128) {
        int ex = sc[tid] - hist[tid];
        cursor[tid] = ex;
        int node = B * 128 + tid;
        if (node < N_NODES) rowstart[node] = base + ex;
    }
    __syncthreads();
    for (int i = tid; i < n; i += 256) {
        int v = ein[i];
        int p = atomicAdd(&cursor[v & BMASK], 1);
        eout[p] = v >> BSH;
    }
    __syncthreads();
    for (int i = tid; i < n; i += 256) sorted_src[base + i] = eout[i];
}

// ---------------- W1 -> fp16 transposed [col][k] ----------------

__global__ __launch_bounds__(256) void k_w1half(const float* __restrict__ W1,
                                                _Float16* __restrict__ W1T) {
    int idx = blockIdx.x * 256 + threadIdx.x;   // 32768 total
    int k = idx >> 7, c = idx & 127;
    W1T[c * 256 + k] = (_Float16)W1[idx];
}

// ---------------- Layer 1 GEMM via MFMA fp16: feat1 = x @ W1, fused el1/er1 ----

__global__ __launch_bounds__(256) void k_gemm1(
        const float* __restrict__ x, const _Float16* __restrict__ W1T,
        const float* __restrict__ al1, const float* __restrict__ ar1,
        __half* __restrict__ feat1h, float* __restrict__ el1, float* __restrict__ er1) {
    __shared__ v8h As[64 * 4];    // 64 nodes x 32k fp16, 4 KB
    __shared__ v8h Bs[128 * 4];   // 128 cols x 32k fp16, 8 KB
    int tid = threadIdx.x;
    int nb = blockIdx.x * 64;
    int wid = tid >> 6, lane = tid & 63;
    int wm = wid & 1, wn = wid >> 1;      // wave tile: rows wm*32.., cols wn*64..
    int q = lane >> 4, lm = lane & 15;

    int anode = tid >> 2, ach = tid & 3;
    int gnode = nb + anode; if (gnode >= N_NODES) gnode = N_NODES - 1;
    const float4* xrow = (const float4*)(x + (size_t)gnode * FIN);
    int bc = tid >> 2, bch = tid & 3;

    v4f acc[2][4];
    #pragma unroll
    for (int mt = 0; mt < 2; mt++)
        #pragma unroll
        for (int nt = 0; nt < 4; nt++) acc[mt][nt] = (v4f)(0.f);

    float4 xa0 = xrow[ach * 2];
    float4 xa1 = xrow[ach * 2 + 1];
    F4H8 wb0, wb1;
    wb0.f = *(const float4*)(W1T + bc * 256 + bch * 8);
    wb1.f = *(const float4*)(W1T + (bc + 64) * 256 + bch * 8);

    for (int step = 0; step < 8; step++) {
        __syncthreads();
        {
            v8h av;
            av[0] = (_Float16)xa0.x; av[1] = (_Float16)xa0.y;
            av[2] = (_Float16)xa0.z; av[3] = (_Float16)xa0.w;
            av[4] = (_Float16)xa1.x; av[5] = (_Float16)xa1.y;
            av[6] = (_Float16)xa1.z; av[7] = (_Float16)xa1.w;
            As[anode * 4 + (ach ^ (anode & 3))] = av;
            Bs[bc * 4 + (bch ^ (bc & 3))] = wb0.h;
            Bs[(bc + 64) * 4 + (bch ^ (bc & 3))] = wb1.h;
        }
        __syncthreads();
        if (step < 7) {
            int k0 = (step + 1) * 32;
            xa0 = xrow[(k0 >> 2) + ach * 2];
            xa1 = xrow[(k0 >> 2) + ach * 2 + 1];
            wb0.f = *(const float4*)(W1T + bc * 256 + k0 + bch * 8);
            wb1.f = *(const float4*)(W1T + (bc + 64) * 256 + k0 + bch * 8);
        }
        v8h af[2], bf[4];
        #pragma unroll
        for (int mt = 0; mt < 2; mt++) {
            int nl = wm * 32 + mt * 16 + lm;
            af[mt] = As[nl * 4 + (q ^ (nl & 3))];
        }
        #pragma unroll
        for (int nt = 0; nt < 4; nt++) {
            int cl = wn * 64 + nt * 16 + lm;
            bf[nt] = Bs[cl * 4 + (q ^ (cl & 3))];
        }
        #pragma unroll
        for (int mt = 0; mt < 2; mt++)
            #pragma unroll
            for (int nt = 0; nt < 4; nt++)
                acc[mt][nt] = __builtin_amdgcn_mfma_f32_16x16x32_f16(
                    af[mt], bf[nt], acc[mt][nt], 0, 0, 0);
    }

    float alv[4], arv[4];
    #pragma unroll
    for (int nt = 0; nt < 4; nt++) {
        alv[nt] = al1[wn * 64 + nt * 16 + lm];
        arv[nt] = ar1[wn * 64 + nt * 16 + lm];
    }
    int h0 = 2 * wn, h1 = 2 * wn + 1;
    #pragma unroll
    for (int mt = 0; mt < 2; mt++) {
        #pragma unroll
        for (int r = 0; r < 4; r++) {
            int node = nb + wm * 32 + mt * 16 + q * 4 + r;
            bool ok = node < N_NODES;
            float v0 = acc[mt][0][r], v1 = acc[mt][1][r];
            float v2 = acc[mt][2][r], v3 = acc[mt][3][r];
            if (ok) {
                __half* fp = feat1h + (size_t)node * HD + wn * 64 + lm;
                fp[0]  = __float2half(v0);
                fp[16] = __float2half(v1);
                fp[32] = __float2half(v2);
                fp[48] = __float2half(v3);
            }
            float pl0 = v0 * alv[0] + v1 * alv[1];
            float pr0 = v0 * arv[0] + v1 * arv[1];
            float pl1 = v2 * alv[2] + v3 * alv[3];
            float pr1 = v2 * arv[2] + v3 * arv[3];
            #pragma unroll
            for (int m = 1; m <= 8; m <<= 1) {
                pl0 += __shfl_xor(pl0, m); pr0 += __shfl_xor(pr0, m);
                pl1 += __shfl_xor(pl1, m); pr1 += __shfl_xor(pr1, m);
            }
            if (ok && lm == 0) {
                el1[node * 4 + h0] = pl0; er1[node * 4 + h0] = pr0;
                el1[node * 4 + h1] = pl1; er1[node * 4 + h1] = pr1;
            }
        }
    }
}

// ---------------- Layer 1 aggregation: wave per dst, 16 edges in flight ----------------

__global__ __launch_bounds__(256) void k_agg1(
        const int* __restrict__ rowstart, const int* __restrict__ sorted_src,
        const float* __restrict__ el1, const float* __restrict__ er1,
        const __half* __restrict__ feat1h, const float* __restrict__ b1,
        float* __restrict__ h) {
    int tid = threadIdx.x;
    int d = blockIdx.x * 4 + (tid >> 6);   // 50000 % 4 == 0
    int lane = tid & 63;
    int eg = lane >> 4;                    // edge group 0..3
    int cl = lane & 15;                    // col-lane: cols 8*cl..8*cl+7
    int head = cl >> 2;
    float er = er1[d * 4 + head];
    int start = rowstart[d], end = rowstart[d + 1];
    float acc[8];
    #pragma unroll
    for (int k = 0; k < 8; k++) acc[k] = 0.f;
    float wsum = 0.f;

    for (int i = start; i < end; i += 16) {
        int s[4]; bool ok[4];
        #pragma unroll
        for (int u = 0; u < 4; u++) {
            int e = i + 4 * u + eg;
            ok[u] = e < end;
            int ec = ok[u] ? e : end - 1;
            s[u] = sorted_src[ec];
        }
        float elv[4];
        #pragma unroll
        for (int u = 0; u < 4; u++) elv[u] = el1[s[u] * 4 + head];
        float4 r[4];
        #pragma unroll
        for (int u = 0; u < 4; u++)
            r[u] = *(const float4*)(feat1h + (size_t)s[u] * HD + cl * 8);
        #pragma unroll
        for (int u = 0; u < 4; u++) {
            float w = ok[u] ? lexp(elv[u] + er) : 0.f;
            const __half2* p = (const __half2*)&r[u];
            #pragma unroll
            for (int q = 0; q < 4; q++) {
                float2 f = __half22float2(p[q]);
                acc[2 * q]     += w * f.x;
                acc[2 * q + 1] += w * f.y;
            }
            wsum += w;
        }
    }
    #pragma unroll
    for (int k = 0; k < 8; k++) {
        acc[k] += __shfl_xor(acc[k], 16);
        acc[k] += __shfl_xor(acc[k], 32);
    }
    wsum += __shfl_xor(wsum, 16);
    wsum += __shfl_xor(wsum, 32);
    if (eg == 0) {
        float inv = 1.f / fmaxf(wsum, 1e-9f);
        float v[8];
        #pragma unroll
        for (int k = 0; k < 8; k++) v[k] = elu1(acc[k] * inv + b1[cl * 8 + k]);
        float4* hp = (float4*)(h + (size_t)d * HD + cl * 8);
        hp[0] = make_float4(v[0], v[1], v[2], v[3]);
        hp[1] = make_float4(v[4], v[5], v[6], v[7]);
    }
}

// ---------------- Layer 2 GEMM: feat2 = h @ W2, fused el2/er2 ----------------

__global__ __launch_bounds__(256) void k_gemm2(
        const float* __restrict__ h, const float* __restrict__ W2,
        const float* __restrict__ al2, const float* __restrict__ ar2,
        float* __restrict__ feat2, float* __restrict__ el2, float* __restrict__ er2) {
    __shared__ float hs[16 * 132];
    __shared__ float w2t[16 * 132];
    int tid = threadIdx.x;
    int nb = blockIdx.x * 16;  // 50000 % 16 == 0
    for (int idx = tid; idx < 512; idx += 256) {
        int row = idx >> 5, kk = idx & 31;
        ((float4*)(hs + row * 132))[kk] = ((const float4*)h)[(size_t)(nb + row) * 32 + kk];
    }
    for (int idx = tid; idx < 2048; idx += 256) {
        int k = idx >> 4, c = idx & 15;
        w2t[c * 132 + k] = W2[idx];
    }
    __syncthreads();
    int nl = tid >> 4, col = tid & 15;
    const float4* hv = (const float4*)(hs + nl * 132);
    const float4* wv = (const float4*)(w2t + col * 132);
    float acc = 0.f;
    #pragma unroll
    for (int kk = 0; kk < 32; kk++) {
        float4 a = hv[kk], w = wv[kk];
        acc += a.x * w.x + a.y * w.y + a.z * w.z + a.w * w.w;
    }
    int node = nb + nl;
    feat2[node * 16 + col] = acc;
    float pl = acc * al2[col], pr = acc * ar2[col];
    #pragma unroll
    for (int m = 8; m >= 1; m >>= 1) {
        pl += __shfl_xor(pl, m);
        pr += __shfl_xor(pr, m);
    }
    if (col == 0) { el2[node] = pl; er2[node] = pr; }
}

// ---------------- Layer 2 aggregation: wave per dst, 16 edges x 4 col-lanes ----------------

__global__ __launch_bounds__(256) void k_agg2(
        const int* __restrict__ rowstart, const int* __restrict__ sorted_src,
        const float* __restrict__ el2, const float* __restrict__ er2,
        const float* __restrict__ feat2, const float* __restrict__ b2,
        float* __restrict__ out) {
    int tid = threadIdx.x;
    int d = blockIdx.x * 4 + (tid >> 6);   // 50000 % 4 == 0
    int lane = tid & 63;
    int eg = lane >> 2;                    // edge group 0..15
    int cq = lane & 3;                     // cols 4*cq..4*cq+3
    float er = er2[d];
    int start = rowstart[d], end = rowstart[d + 1];
    float4 acc = make_float4(0.f, 0.f, 0.f, 0.f);
    float wsum = 0.f;
    for (int i = start; i < end; i += 16) {
        int e = i + eg;
        bool ok = e < end;
        int ec = ok ? e : end - 1;
        int s = sorted_src[ec];
        float elv = el2[s];
        float4 f = ((const float4*)feat2)[(size_t)s * 4 + cq];
        float ev = elv + er;
        float wr = __expf(ev > 0.f ? ev : NEG * ev);
        float w = ok ? wr : 0.f;
        acc.x += w * f.x; acc.y += w * f.y; acc.z += w * f.z; acc.w += w * f.w;
        wsum += w;
    }
    #pragma unroll
    for (int m = 4; m <= 32; m <<= 1) {
        acc.x += __shfl_xor(acc.x, m);
        acc.y += __shfl_xor(acc.y, m);
        acc.z += __shfl_xor(acc.z, m);
        acc.w += __shfl_xor(acc.w, m);
        wsum  += __shfl_xor(wsum, m);
    }
    if (lane < 4) {
        float inv = 1.f / fmaxf(wsum, 1e-9f);
        float4 bv = ((const float4*)b2)[cq];
        float4 o = make_float4(acc.x * inv + bv.x, acc.y * inv + bv.y,
                               acc.z * inv + bv.z, acc.w * inv + bv.w);
        ((float4*)out)[(size_t)d * 4 + cq] = o;
    }
}

// ---------------- launch ----------------

extern "C" void kernel_launch(void* const* d_in, const int* in_sizes, int n_in,
                              void* d_out, int out_size, void* d_ws, size_t ws_size,
                              hipStream_t stream) {
    const float* x   = (const float*)d_in[0];
    const int*   src = (const int*)d_in[1];
    const int*   dst = (const int*)d_in[2];
    const float* W1  = (const float*)d_in[3];
    const float* b1  = (const float*)d_in[4];
    const float* al1 = (const float*)d_in[5];
    const float* ar1 = (const float*)d_in[6];
    const float* W2  = (const float*)d_in[7];
    const float* b2  = (const float*)d_in[8];
    const float* al2 = (const float*)d_in[9];
    const float* ar2 = (const float*)d_in[10];
    float* out = (float*)d_out;

    char* ws = (char*)d_ws;
    size_t off = 0;
    auto alloc = [&](size_t bytes) -> char* {
        char* p = ws + off;
        off += (bytes + 255) & ~(size_t)255;
        return p;
    };
    __half* feat1h     = (__half*)alloc((size_t)N_NODES * HD * 2);
    _Float16* W1T      = (_Float16*)alloc((size_t)FIN * HD * 2);
    float* h           = (float*)alloc((size_t)N_NODES * HD * 4);
    float* el1         = (float*)alloc((size_t)N_NODES * 4 * 4);
    float* er1         = (float*)alloc((size_t)N_NODES * 4 * 4);
    float* feat2       = (float*)alloc((size_t)N_NODES * C2 * 4);
    float* el2         = (float*)alloc((size_t)N_NODES * 4);
    float* er2         = (float*)alloc((size_t)N_NODES * 4);
    int*   ghist       = (int*)alloc((size_t)NBUCK * NBLK * 4);
    int*   bucket_tot  = (int*)alloc((size_t)NBUCK * 4);
    int*   bucket_base = (int*)alloc((size_t)(NBUCK + 1) * 4);
    int*   rowstart    = (int*)alloc((size_t)(N_NODES + 1) * 4);
    int*   ebuf        = (int*)alloc((size_t)N_EDGES * 4);
    int*   sorted_src  = (int*)alloc((size_t)N_EDGES * 4);

    k_bhist<<<NBLK, 256, 0, stream>>>(dst, ghist);
    k_bscan1<<<NBUCK, 256, 0, stream>>>(ghist, bucket_tot);
    k_bscan2<<<1, 512, 0, stream>>>(bucket_tot, bucket_base, rowstart);
    k_bscatter<<<NBLK, 256, 0, stream>>>(src, dst, ghist, bucket_base, ebuf);
    k_bsort<<<NBUCK, 256, 0, stream>>>(ebuf, bucket_base, sorted_src, rowstart);
    k_w1half<<<128, 256, 0, stream>>>(W1, W1T);
    k_gemm1<<<(N_NODES + 63) / 64, 256, 0, stream>>>(x, W1T, al1, ar1, feat1h, el1, er1);
    k_agg1<<<N_NODES / 4, 256, 0, stream>>>(rowstart, sorted_src, el1, er1, feat1h, b1, h);
    k_gemm2<<<N_NODES / 16, 256, 0, stream>>>(h, W2, al2, ar2, feat2, el2, er2);
    k_agg2<<<N_NODES / 4, 256, 0, stream>>>(rowstart, sorted_src, el2, er2, feat2, b2, out);
}